// Round 1
// baseline (729.183 us; speedup 1.0000x reference)
//
#include <hip/hip_runtime.h>
#include <cstddef>

#define NSRC 50000
#define NDST 50000
#define NEDGE 500000
#define DIM 128
#define EDIM 11
#define BN_EPS 1e-5f

// ---------------- workspace layout (floats) ----------------
// hs       [NSRC*DIM]
// s_score  [NSRC]
// d_score  [NDST]
// ea       [NEDGE]
// denom    [NDST]
// colsum   [128]
// colsq    [128]
// wd_vec   [128]
// we_vec   [16]
// scal     [4]      scal[0]=b_dst.aw_d  scal[1]=b_edge.aw_e+attn_b
// scale    [128]
// shift    [128]

#define OFF_HS      0
#define OFF_SSCORE  (OFF_HS + (size_t)NSRC*DIM)
#define OFF_DSCORE  (OFF_SSCORE + NSRC)
#define OFF_EA      (OFF_DSCORE + NDST)
#define OFF_DENOM   (OFF_EA + NEDGE)
#define OFF_COLSUM  (OFF_DENOM + NDST)
#define OFF_COLSQ   (OFF_COLSUM + 128)
#define OFF_WDVEC   (OFF_COLSQ + 128)
#define OFF_WEVEC   (OFF_WDVEC + 128)
#define OFF_SCAL    (OFF_WEVEC + 16)
#define OFF_SCALE   (OFF_SCAL + 4)
#define OFF_SHIFT   (OFF_SCALE + 128)

// Precompute combined attention vectors:
// wd_vec[k] = sum_d W_dst[k][d]*aw_d[d] ; we_vec[k] = sum_d W_edge[k][d]*aw_e[d]
// scal[0] = b_dst.aw_d ; scal[1] = b_edge.aw_e + attn_b
__global__ void k_prep(const float* __restrict__ W_dst, const float* __restrict__ b_dst,
                       const float* __restrict__ W_edge, const float* __restrict__ b_edge,
                       const float* __restrict__ attn_w, const float* __restrict__ attn_b,
                       float* __restrict__ wd_vec, float* __restrict__ we_vec,
                       float* __restrict__ scal) {
    int t = threadIdx.x;  // 128 threads
    float acc = 0.f;
    for (int d = 0; d < DIM; ++d) acc += W_dst[t * DIM + d] * attn_w[DIM + d];
    wd_vec[t] = acc;
    if (t < EDIM) {
        float e = 0.f;
        for (int d = 0; d < DIM; ++d) e += W_edge[t * DIM + d] * attn_w[2 * DIM + d];
        we_vec[t] = e;
    }
    __shared__ float red[128];
    red[t] = b_dst[t] * attn_w[DIM + t];
    __syncthreads();
    for (int s = 64; s > 0; s >>= 1) { if (t < s) red[t] += red[t + s]; __syncthreads(); }
    if (t == 0) scal[0] = red[0];
    __syncthreads();
    red[t] = b_edge[t] * attn_w[2 * DIM + t];
    __syncthreads();
    for (int s = 64; s > 0; s >>= 1) { if (t < s) red[t] += red[t + s]; __syncthreads(); }
    if (t == 0) scal[1] = red[0] + attn_b[0];
}

// hs = src_feat @ W_src + b_src  (fp32 GEMM, 32 rows/block)
// fused: s_score[row] = hs[row] . attn_w[0:128]
__global__ __launch_bounds__(256) void k_hs(const float* __restrict__ A,
                                            const float* __restrict__ W,
                                            const float* __restrict__ bias,
                                            const float* __restrict__ attn_w,
                                            float* __restrict__ hs,
                                            float* __restrict__ s_score) {
    __shared__ float As[32][132];  // padded: stride 132 -> conflict-free reads
    int t = threadIdx.x;
    int row0 = blockIdx.x * 32;

    // stage 32x128 A-tile: 1024 float4 loads, 4 per thread
    #pragma unroll
    for (int i = 0; i < 4; ++i) {
        int f = t + 256 * i;        // 0..1023
        int r = f >> 5;             // 32 float4 per row
        int c4 = f & 31;
        int gr = row0 + r;
        float4 v = make_float4(0.f, 0.f, 0.f, 0.f);
        if (gr < NSRC) v = *reinterpret_cast<const float4*>(A + (size_t)gr * DIM + c4 * 4);
        reinterpret_cast<float4*>(&As[r][0])[c4] = v;   // row stride 528B, 16B-aligned
    }
    __syncthreads();

    int r = t >> 3, cg = t & 7, c0 = cg * 16;
    float acc[16];
    #pragma unroll
    for (int i = 0; i < 16; ++i) acc[i] = bias[c0 + i];

    #pragma unroll 2
    for (int k = 0; k < DIM; ++k) {
        float a = As[r][k];
        const float4* wr = reinterpret_cast<const float4*>(W + (size_t)k * DIM + c0);
        #pragma unroll
        for (int i = 0; i < 4; ++i) {
            float4 w = wr[i];
            acc[4 * i + 0] += a * w.x;
            acc[4 * i + 1] += a * w.y;
            acc[4 * i + 2] += a * w.z;
            acc[4 * i + 3] += a * w.w;
        }
    }

    int gr = row0 + r;
    if (gr < NSRC) {
        float4* o = reinterpret_cast<float4*>(hs + (size_t)gr * DIM + c0);
        #pragma unroll
        for (int i = 0; i < 4; ++i)
            o[i] = make_float4(acc[4 * i], acc[4 * i + 1], acc[4 * i + 2], acc[4 * i + 3]);
        float p = 0.f;
        #pragma unroll
        for (int i = 0; i < 16; ++i) p += acc[i] * attn_w[c0 + i];
        p += __shfl_xor(p, 1);
        p += __shfl_xor(p, 2);
        p += __shfl_xor(p, 4);
        if (cg == 0) s_score[gr] = p;
    }
}

// d_score = dst_feat . wd_vec + scal[0]   (8 lanes per row)
__global__ __launch_bounds__(256) void k_dscore(const float* __restrict__ B,
                                                const float* __restrict__ wd_vec,
                                                const float* __restrict__ scal,
                                                float* __restrict__ d_score) {
    int t = threadIdx.x;
    int row = blockIdx.x * 32 + (t >> 3);
    int c0 = (t & 7) * 16;
    if (row >= NDST) return;
    const float4* x = reinterpret_cast<const float4*>(B + (size_t)row * DIM + c0);
    const float4* w = reinterpret_cast<const float4*>(wd_vec + c0);
    float p = 0.f;
    #pragma unroll
    for (int i = 0; i < 4; ++i) {
        float4 a = x[i], b = w[i];
        p += a.x * b.x + a.y * b.y + a.z * b.z + a.w * b.w;
    }
    p += __shfl_xor(p, 1);
    p += __shfl_xor(p, 2);
    p += __shfl_xor(p, 4);
    if ((t & 7) == 0) d_score[row] = p + scal[0];
}

// per-edge logit + exp, accumulate softmax denominator
__global__ void k_edge(const float* __restrict__ ef, const int* __restrict__ src_idx,
                       const int* __restrict__ dst_idx, const float* __restrict__ s_score,
                       const float* __restrict__ d_score, const float* __restrict__ we_vec,
                       const float* __restrict__ scal,
                       float* __restrict__ ea, float* __restrict__ denom) {
    int e = blockIdx.x * blockDim.x + threadIdx.x;
    if (e >= NEDGE) return;
    int s = src_idx[e], d = dst_idx[e];
    const float* er = ef + (size_t)e * EDIM;
    float a = scal[1];
    #pragma unroll
    for (int k = 0; k < EDIM; ++k) a += er[k] * we_vec[k];
    a += s_score[s] + d_score[d];
    // weights are 0.05-scaled => |a| is O(3); exp without max-subtraction is
    // mathematically identical to the reference softmax and overflow-free.
    float x = expf(a);
    ea[e] = x;
    atomicAdd(&denom[d], x);
}

// h_new[dst] += (ea/denom[dst]) * hs[src]   — one wave (64 lanes) per edge, float2/lane
__global__ __launch_bounds__(256) void k_scatter(const float* __restrict__ hs,
                                                 const int* __restrict__ src_idx,
                                                 const int* __restrict__ dst_idx,
                                                 const float* __restrict__ ea,
                                                 const float* __restrict__ denom,
                                                 float* __restrict__ h_new) {
    int wave = (blockIdx.x * blockDim.x + threadIdx.x) >> 6;
    int lane = threadIdx.x & 63;
    int nwaves = (gridDim.x * blockDim.x) >> 6;
    for (int e = wave; e < NEDGE; e += nwaves) {
        int s = src_idx[e], d = dst_idx[e];
        float attn = ea[e] / denom[d];
        float2 v = reinterpret_cast<const float2*>(hs + (size_t)s * DIM)[lane];
        atomicAdd(&h_new[(size_t)d * DIM + lane * 2 + 0], attn * v.x);
        atomicAdd(&h_new[(size_t)d * DIM + lane * 2 + 1], attn * v.y);
    }
}

// per-column sum / sumsq over h_new
__global__ __launch_bounds__(256) void k_bnstats(const float* __restrict__ h,
                                                 float* __restrict__ colsum,
                                                 float* __restrict__ colsq) {
    int col = threadIdx.x & 127;
    int rp = threadIdx.x >> 7;  // 0..1
    float s = 0.f, q = 0.f;
    for (int r = blockIdx.x * 2 + rp; r < NDST; r += gridDim.x * 2) {
        float x = h[(size_t)r * DIM + col];
        s += x;
        q += x * x;
    }
    __shared__ float ls[2][128], lq[2][128];
    ls[rp][col] = s;
    lq[rp][col] = q;
    __syncthreads();
    if (rp == 0) {
        atomicAdd(&colsum[col], ls[0][col] + ls[1][col]);
        atomicAdd(&colsq[col], lq[0][col] + lq[1][col]);
    }
}

// scale/shift per column
__global__ void k_bnscale(const float* __restrict__ colsum, const float* __restrict__ colsq,
                          const float* __restrict__ gamma, const float* __restrict__ beta,
                          float* __restrict__ scale, float* __restrict__ shift) {
    int t = threadIdx.x;  // 128
    const float invN = 1.f / (float)NDST;
    float mean = colsum[t] * invN;
    float var = colsq[t] * invN - mean * mean;
    float sc = gamma[t] * rsqrtf(var + BN_EPS);
    scale[t] = sc;
    shift[t] = beta[t] - mean * sc;
}

// in-place BN + LeakyReLU on d_out
__global__ void k_bnfinal(float* __restrict__ h, const float* __restrict__ scale,
                          const float* __restrict__ shift, const float* __restrict__ alpha_p) {
    const size_t total4 = (size_t)NDST * DIM / 4;
    float alpha = alpha_p[0];
    size_t stride = (size_t)gridDim.x * blockDim.x;
    for (size_t i = blockIdx.x * blockDim.x + threadIdx.x; i < total4; i += stride) {
        float4 x = reinterpret_cast<float4*>(h)[i];
        int c0 = ((int)(i & 31)) * 4;
        float y0 = x.x * scale[c0 + 0] + shift[c0 + 0];
        float y1 = x.y * scale[c0 + 1] + shift[c0 + 1];
        float y2 = x.z * scale[c0 + 2] + shift[c0 + 2];
        float y3 = x.w * scale[c0 + 3] + shift[c0 + 3];
        float4 o;
        o.x = y0 >= 0.f ? y0 : alpha * y0;
        o.y = y1 >= 0.f ? y1 : alpha * y1;
        o.z = y2 >= 0.f ? y2 : alpha * y2;
        o.w = y3 >= 0.f ? y3 : alpha * y3;
        reinterpret_cast<float4*>(h)[i] = o;
    }
}

extern "C" void kernel_launch(void* const* d_in, const int* in_sizes, int n_in,
                              void* d_out, int out_size, void* d_ws, size_t ws_size,
                              hipStream_t stream) {
    const float* src_feat   = (const float*)d_in[0];
    const float* dst_feat   = (const float*)d_in[1];
    const float* edge_feats = (const float*)d_in[2];
    const int*   src_idx    = (const int*)d_in[3];
    const int*   dst_idx    = (const int*)d_in[4];
    const float* W_src      = (const float*)d_in[5];
    const float* b_src      = (const float*)d_in[6];
    const float* W_dst      = (const float*)d_in[7];
    const float* b_dst      = (const float*)d_in[8];
    const float* W_edge     = (const float*)d_in[9];
    const float* b_edge     = (const float*)d_in[10];
    const float* attn_w     = (const float*)d_in[11];
    const float* attn_b     = (const float*)d_in[12];
    const float* gamma      = (const float*)d_in[13];
    const float* beta       = (const float*)d_in[14];
    const float* alpha      = (const float*)d_in[15];

    float* ws      = (float*)d_ws;
    float* hs      = ws + OFF_HS;
    float* s_score = ws + OFF_SSCORE;
    float* d_score = ws + OFF_DSCORE;
    float* ea      = ws + OFF_EA;
    float* denom   = ws + OFF_DENOM;
    float* colsum  = ws + OFF_COLSUM;
    float* colsq   = ws + OFF_COLSQ;
    float* wd_vec  = ws + OFF_WDVEC;
    float* we_vec  = ws + OFF_WEVEC;
    float* scal    = ws + OFF_SCAL;
    float* scale   = ws + OFF_SCALE;
    float* shift   = ws + OFF_SHIFT;

    float* h_new = (float*)d_out;  // d_out doubles as the h_new accumulator

    // zero accumulators every call (harness does not re-poison between replays)
    hipMemsetAsync(denom, 0, NDST * sizeof(float), stream);
    hipMemsetAsync(colsum, 0, 256 * sizeof(float), stream);  // colsum+colsq contiguous
    hipMemsetAsync(h_new, 0, (size_t)NDST * DIM * sizeof(float), stream);

    k_prep<<<1, 128, 0, stream>>>(W_dst, b_dst, W_edge, b_edge, attn_w, attn_b,
                                  wd_vec, we_vec, scal);
    k_hs<<<(NSRC + 31) / 32, 256, 0, stream>>>(src_feat, W_src, b_src, attn_w, hs, s_score);
    k_dscore<<<(NDST + 31) / 32, 256, 0, stream>>>(dst_feat, wd_vec, scal, d_score);
    k_edge<<<(NEDGE + 255) / 256, 256, 0, stream>>>(edge_feats, src_idx, dst_idx,
                                                    s_score, d_score, we_vec, scal,
                                                    ea, denom);
    k_scatter<<<1024, 256, 0, stream>>>(hs, src_idx, dst_idx, ea, denom, h_new);
    k_bnstats<<<256, 256, 0, stream>>>(h_new, colsum, colsq);
    k_bnscale<<<1, 128, 0, stream>>>(colsum, colsq, gamma, beta, scale, shift);
    k_bnfinal<<<2048, 256, 0, stream>>>(h_new, scale, shift, alpha);
}

// Round 2
// 527.539 us; speedup vs baseline: 1.3822x; 1.3822x over previous
//
#include <hip/hip_runtime.h>
#include <cstddef>

#define NSRC 50000
#define NDST 50000
#define NEDGE 500000
#define DIM 128
#define EDIM 11
#define BN_EPS 1e-5f

// ---------------- workspace layout (4B elems) ----------------
#define OFF_HS      0
#define OFF_SSCORE  (OFF_HS + (size_t)NSRC*DIM)
#define OFF_DSCORE  (OFF_SSCORE + NSRC)
#define OFF_DEG     (OFF_DSCORE + NDST)
#define OFF_OFFS    (OFF_DEG + NDST)
#define OFF_CURSOR  (OFF_OFFS + NDST + 1)
#define OFF_SSRC    (OFF_CURSOR + NDST)
#define OFF_SW      (OFF_SSRC + NEDGE)
#define OFF_COLSUM  (OFF_SW + NEDGE)
#define OFF_COLSQ   (OFF_COLSUM + 128)
#define OFF_WDVEC   (OFF_COLSQ + 128)
#define OFF_WEVEC   (OFF_WDVEC + 128)
#define OFF_SCAL    (OFF_WEVEC + 16)
#define OFF_SCALE   (OFF_SCAL + 4)
#define OFF_SHIFT   (OFF_SCALE + 128)

// wd_vec[k] = sum_d W_dst[k][d]*aw_d[d] ; we_vec[k] = sum_d W_edge[k][d]*aw_e[d]
// scal[0] = b_dst.aw_d ; scal[1] = b_edge.aw_e + attn_b
__global__ void k_prep(const float* __restrict__ W_dst, const float* __restrict__ b_dst,
                       const float* __restrict__ W_edge, const float* __restrict__ b_edge,
                       const float* __restrict__ attn_w, const float* __restrict__ attn_b,
                       float* __restrict__ wd_vec, float* __restrict__ we_vec,
                       float* __restrict__ scal) {
    int t = threadIdx.x;  // 128 threads
    float acc = 0.f;
    for (int d = 0; d < DIM; ++d) acc += W_dst[t * DIM + d] * attn_w[DIM + d];
    wd_vec[t] = acc;
    if (t < EDIM) {
        float e = 0.f;
        for (int d = 0; d < DIM; ++d) e += W_edge[t * DIM + d] * attn_w[2 * DIM + d];
        we_vec[t] = e;
    }
    __shared__ float red[128];
    red[t] = b_dst[t] * attn_w[DIM + t];
    __syncthreads();
    for (int s = 64; s > 0; s >>= 1) { if (t < s) red[t] += red[t + s]; __syncthreads(); }
    if (t == 0) scal[0] = red[0];
    __syncthreads();
    red[t] = b_edge[t] * attn_w[2 * DIM + t];
    __syncthreads();
    for (int s = 64; s > 0; s >>= 1) { if (t < s) red[t] += red[t + s]; __syncthreads(); }
    if (t == 0) scal[1] = red[0] + attn_b[0];
}

// hs = src_feat @ W_src + b_src  (fp32, 32 rows/block)
// fused: s_score[row] = hs[row] . attn_w[0:128]
__global__ __launch_bounds__(256) void k_hs(const float* __restrict__ A,
                                            const float* __restrict__ W,
                                            const float* __restrict__ bias,
                                            const float* __restrict__ attn_w,
                                            float* __restrict__ hs,
                                            float* __restrict__ s_score) {
    __shared__ float As[32][132];
    int t = threadIdx.x;
    int row0 = blockIdx.x * 32;

    #pragma unroll
    for (int i = 0; i < 4; ++i) {
        int f = t + 256 * i;
        int r = f >> 5;
        int c4 = f & 31;
        int gr = row0 + r;
        float4 v = make_float4(0.f, 0.f, 0.f, 0.f);
        if (gr < NSRC) v = *reinterpret_cast<const float4*>(A + (size_t)gr * DIM + c4 * 4);
        reinterpret_cast<float4*>(&As[r][0])[c4] = v;
    }
    __syncthreads();

    int r = t >> 3, cg = t & 7, c0 = cg * 16;
    float acc[16];
    #pragma unroll
    for (int i = 0; i < 16; ++i) acc[i] = bias[c0 + i];

    #pragma unroll 2
    for (int k = 0; k < DIM; ++k) {
        float a = As[r][k];
        const float4* wr = reinterpret_cast<const float4*>(W + (size_t)k * DIM + c0);
        #pragma unroll
        for (int i = 0; i < 4; ++i) {
            float4 w = wr[i];
            acc[4 * i + 0] += a * w.x;
            acc[4 * i + 1] += a * w.y;
            acc[4 * i + 2] += a * w.z;
            acc[4 * i + 3] += a * w.w;
        }
    }

    int gr = row0 + r;
    if (gr < NSRC) {
        float4* o = reinterpret_cast<float4*>(hs + (size_t)gr * DIM + c0);
        #pragma unroll
        for (int i = 0; i < 4; ++i)
            o[i] = make_float4(acc[4 * i], acc[4 * i + 1], acc[4 * i + 2], acc[4 * i + 3]);
        float p = 0.f;
        #pragma unroll
        for (int i = 0; i < 16; ++i) p += acc[i] * attn_w[c0 + i];
        p += __shfl_xor(p, 1);
        p += __shfl_xor(p, 2);
        p += __shfl_xor(p, 4);
        if (cg == 0) s_score[gr] = p;
    }
}

// d_score = dst_feat . wd_vec + scal[0]
__global__ __launch_bounds__(256) void k_dscore(const float* __restrict__ B,
                                                const float* __restrict__ wd_vec,
                                                const float* __restrict__ scal,
                                                float* __restrict__ d_score) {
    int t = threadIdx.x;
    int row = blockIdx.x * 32 + (t >> 3);
    int c0 = (t & 7) * 16;
    if (row >= NDST) return;
    const float4* x = reinterpret_cast<const float4*>(B + (size_t)row * DIM + c0);
    const float4* w = reinterpret_cast<const float4*>(wd_vec + c0);
    float p = 0.f;
    #pragma unroll
    for (int i = 0; i < 4; ++i) {
        float4 a = x[i], b = w[i];
        p += a.x * b.x + a.y * b.y + a.z * b.z + a.w * b.w;
    }
    p += __shfl_xor(p, 1);
    p += __shfl_xor(p, 2);
    p += __shfl_xor(p, 4);
    if ((t & 7) == 0) d_score[row] = p + scal[0];
}

// degree histogram over dst
__global__ void k_hist(const int* __restrict__ dst_idx, int* __restrict__ deg) {
    int e = blockIdx.x * blockDim.x + threadIdx.x;
    if (e < NEDGE) atomicAdd(&deg[dst_idx[e]], 1);
}

// single-block exclusive scan of deg -> off, cursor
__global__ __launch_bounds__(256) void k_scan(const int* __restrict__ deg,
                                              int* __restrict__ off,
                                              int* __restrict__ cursor) {
    __shared__ int part[256];
    int t = threadIdx.x;
    const int CH = (NDST + 255) / 256;  // 196
    int base = t * CH;
    int s = 0;
    for (int i = 0; i < CH; ++i) {
        int idx = base + i;
        if (idx < NDST) s += deg[idx];
    }
    part[t] = s;
    __syncthreads();
    for (int d = 1; d < 256; d <<= 1) {
        int v = (t >= d) ? part[t - d] : 0;
        __syncthreads();
        part[t] += v;
        __syncthreads();
    }
    int run = (t == 0) ? 0 : part[t - 1];
    for (int i = 0; i < CH; ++i) {
        int idx = base + i;
        if (idx < NDST) {
            off[idx] = run;
            cursor[idx] = run;
            run += deg[idx];
        }
    }
    if (t == 255) off[NDST] = run;
}

// per-edge logit + exp, scatter (src, w) into CSR slots
__global__ void k_fill(const float* __restrict__ ef, const int* __restrict__ src_idx,
                       const int* __restrict__ dst_idx, const float* __restrict__ s_score,
                       const float* __restrict__ d_score, const float* __restrict__ we_vec,
                       const float* __restrict__ scal,
                       int* __restrict__ cursor, int* __restrict__ ssrc,
                       float* __restrict__ sw) {
    int e = blockIdx.x * blockDim.x + threadIdx.x;
    if (e >= NEDGE) return;
    int s = src_idx[e], d = dst_idx[e];
    const float* er = ef + (size_t)e * EDIM;
    float a = scal[1];
    #pragma unroll
    for (int k = 0; k < EDIM; ++k) a += er[k] * we_vec[k];
    a += s_score[s] + d_score[d];
    // 0.05-scaled weights => |a| = O(3); exp without max-subtraction is exact
    // softmax algebraically and overflow-free here.
    float x = expf(a);
    int pos = atomicAdd(&cursor[d], 1);
    ssrc[pos] = s;
    sw[pos] = x;
}

// one wave per dst row: gather incoming edges, normalize in-register.
__global__ __launch_bounds__(256) void k_gather(const float* __restrict__ hs,
                                                const int* __restrict__ off,
                                                const int* __restrict__ ssrc,
                                                const float* __restrict__ sw,
                                                float* __restrict__ h_new) {
    int wid = (blockIdx.x * blockDim.x + threadIdx.x) >> 6;
    int lane = threadIdx.x & 63;
    if (wid >= NDST) return;
    int b = off[wid], e2 = off[wid + 1];
    float ax = 0.f, ay = 0.f, sum = 0.f;
    for (int j = b; j < e2; ++j) {
        int s = ssrc[j];
        float w = sw[j];
        sum += w;
        float2 v = reinterpret_cast<const float2*>(hs + (size_t)s * DIM)[lane];
        ax += w * v.x;
        ay += w * v.y;
    }
    float inv = (e2 > b) ? 1.f / sum : 0.f;  // zero-degree dst -> 0 row (matches ref)
    reinterpret_cast<float2*>(h_new + (size_t)wid * DIM)[lane] = make_float2(ax * inv, ay * inv);
}

// per-column sum / sumsq over h_new
__global__ __launch_bounds__(256) void k_bnstats(const float* __restrict__ h,
                                                 float* __restrict__ colsum,
                                                 float* __restrict__ colsq) {
    int col = threadIdx.x & 127;
    int rp = threadIdx.x >> 7;
    float s = 0.f, q = 0.f;
    for (int r = blockIdx.x * 2 + rp; r < NDST; r += gridDim.x * 2) {
        float x = h[(size_t)r * DIM + col];
        s += x;
        q += x * x;
    }
    __shared__ float ls[2][128], lq[2][128];
    ls[rp][col] = s;
    lq[rp][col] = q;
    __syncthreads();
    if (rp == 0) {
        atomicAdd(&colsum[col], ls[0][col] + ls[1][col]);
        atomicAdd(&colsq[col], lq[0][col] + lq[1][col]);
    }
}

__global__ void k_bnscale(const float* __restrict__ colsum, const float* __restrict__ colsq,
                          const float* __restrict__ gamma, const float* __restrict__ beta,
                          float* __restrict__ scale, float* __restrict__ shift) {
    int t = threadIdx.x;  // 128
    const float invN = 1.f / (float)NDST;
    float mean = colsum[t] * invN;
    float var = colsq[t] * invN - mean * mean;
    float sc = gamma[t] * rsqrtf(var + BN_EPS);
    scale[t] = sc;
    shift[t] = beta[t] - mean * sc;
}

__global__ void k_bnfinal(float* __restrict__ h, const float* __restrict__ scale,
                          const float* __restrict__ shift, const float* __restrict__ alpha_p) {
    const size_t total4 = (size_t)NDST * DIM / 4;
    float alpha = alpha_p[0];
    size_t stride = (size_t)gridDim.x * blockDim.x;
    for (size_t i = blockIdx.x * blockDim.x + threadIdx.x; i < total4; i += stride) {
        float4 x = reinterpret_cast<float4*>(h)[i];
        int c0 = ((int)(i & 31)) * 4;
        float y0 = x.x * scale[c0 + 0] + shift[c0 + 0];
        float y1 = x.y * scale[c0 + 1] + shift[c0 + 1];
        float y2 = x.z * scale[c0 + 2] + shift[c0 + 2];
        float y3 = x.w * scale[c0 + 3] + shift[c0 + 3];
        float4 o;
        o.x = y0 >= 0.f ? y0 : alpha * y0;
        o.y = y1 >= 0.f ? y1 : alpha * y1;
        o.z = y2 >= 0.f ? y2 : alpha * y2;
        o.w = y3 >= 0.f ? y3 : alpha * y3;
        reinterpret_cast<float4*>(h)[i] = o;
    }
}

extern "C" void kernel_launch(void* const* d_in, const int* in_sizes, int n_in,
                              void* d_out, int out_size, void* d_ws, size_t ws_size,
                              hipStream_t stream) {
    const float* src_feat   = (const float*)d_in[0];
    const float* dst_feat   = (const float*)d_in[1];
    const float* edge_feats = (const float*)d_in[2];
    const int*   src_idx    = (const int*)d_in[3];
    const int*   dst_idx    = (const int*)d_in[4];
    const float* W_src      = (const float*)d_in[5];
    const float* b_src      = (const float*)d_in[6];
    const float* W_dst      = (const float*)d_in[7];
    const float* b_dst      = (const float*)d_in[8];
    const float* W_edge     = (const float*)d_in[9];
    const float* b_edge     = (const float*)d_in[10];
    const float* attn_w     = (const float*)d_in[11];
    const float* attn_b     = (const float*)d_in[12];
    const float* gamma      = (const float*)d_in[13];
    const float* beta       = (const float*)d_in[14];
    const float* alpha      = (const float*)d_in[15];

    float* ws      = (float*)d_ws;
    float* hs      = ws + OFF_HS;
    float* s_score = ws + OFF_SSCORE;
    float* d_score = ws + OFF_DSCORE;
    int*   deg     = (int*)(ws + OFF_DEG);
    int*   off     = (int*)(ws + OFF_OFFS);
    int*   cursor  = (int*)(ws + OFF_CURSOR);
    int*   ssrc    = (int*)(ws + OFF_SSRC);
    float* sw      = ws + OFF_SW;
    float* colsum  = ws + OFF_COLSUM;
    float* colsq   = ws + OFF_COLSQ;
    float* wd_vec  = ws + OFF_WDVEC;
    float* we_vec  = ws + OFF_WEVEC;
    float* scal    = ws + OFF_SCAL;
    float* scale   = ws + OFF_SCALE;
    float* shift   = ws + OFF_SHIFT;

    float* h_new = (float*)d_out;

    hipMemsetAsync(deg, 0, NDST * sizeof(int), stream);
    hipMemsetAsync(colsum, 0, 256 * sizeof(float), stream);  // colsum+colsq contiguous

    k_prep<<<1, 128, 0, stream>>>(W_dst, b_dst, W_edge, b_edge, attn_w, attn_b,
                                  wd_vec, we_vec, scal);
    k_hs<<<(NSRC + 31) / 32, 256, 0, stream>>>(src_feat, W_src, b_src, attn_w, hs, s_score);
    k_dscore<<<(NDST + 31) / 32, 256, 0, stream>>>(dst_feat, wd_vec, scal, d_score);
    k_hist<<<(NEDGE + 255) / 256, 256, 0, stream>>>(dst_idx, deg);
    k_scan<<<1, 256, 0, stream>>>(deg, off, cursor);
    k_fill<<<(NEDGE + 255) / 256, 256, 0, stream>>>(edge_feats, src_idx, dst_idx,
                                                    s_score, d_score, we_vec, scal,
                                                    cursor, ssrc, sw);
    k_gather<<<(NDST * 64 + 255) / 256, 256, 0, stream>>>(hs, off, ssrc, sw, h_new);
    k_bnstats<<<256, 256, 0, stream>>>(h_new, colsum, colsq);
    k_bnscale<<<1, 128, 0, stream>>>(colsum, colsq, gamma, beta, scale, shift);
    k_bnfinal<<<2048, 256, 0, stream>>>(h_new, scale, shift, alpha);
}

// Round 3
// 331.794 us; speedup vs baseline: 2.1977x; 1.5900x over previous
//
#include <hip/hip_runtime.h>
#include <cstddef>

#define NSRC 50000
#define NDST 50000
#define NEDGE 500000
#define DIM 128
#define EDIM 11
#define BN_EPS 1e-5f

// ---------------- workspace layout (4B elems) ----------------
#define OFF_HS      0
#define OFF_SSCORE  (OFF_HS + (size_t)NSRC*DIM)
#define OFF_DSCORE  (OFF_SSCORE + NSRC)
#define OFF_DEG     (OFF_DSCORE + NDST)
#define OFF_OFFS    (OFF_DEG + NDST)
#define OFF_CURSOR  (OFF_OFFS + NDST + 1)
#define OFF_SSRC    (OFF_CURSOR + NDST)
#define OFF_SW      (OFF_SSRC + NEDGE)
#define OFF_COLSUM  (OFF_SW + NEDGE)
#define OFF_COLSQ   (OFF_COLSUM + 128)
#define OFF_WDVEC   (OFF_COLSQ + 128)
#define OFF_WEVEC   (OFF_WDVEC + 128)
#define OFF_SCAL    (OFF_WEVEC + 16)

// wd_vec[k] = sum_d W_dst[k][d]*aw_d[d] ; we_vec[k] = sum_d W_edge[k][d]*aw_e[d]
// scal[0] = b_dst.aw_d ; scal[1] = b_edge.aw_e + attn_b
__global__ void k_prep(const float* __restrict__ W_dst, const float* __restrict__ b_dst,
                       const float* __restrict__ W_edge, const float* __restrict__ b_edge,
                       const float* __restrict__ attn_w, const float* __restrict__ attn_b,
                       float* __restrict__ wd_vec, float* __restrict__ we_vec,
                       float* __restrict__ scal) {
    int t = threadIdx.x;  // 128 threads
    float acc = 0.f;
    for (int d = 0; d < DIM; ++d) acc += W_dst[t * DIM + d] * attn_w[DIM + d];
    wd_vec[t] = acc;
    if (t < EDIM) {
        float e = 0.f;
        for (int d = 0; d < DIM; ++d) e += W_edge[t * DIM + d] * attn_w[2 * DIM + d];
        we_vec[t] = e;
    }
    __shared__ float red[128];
    red[t] = b_dst[t] * attn_w[DIM + t];
    __syncthreads();
    for (int s = 64; s > 0; s >>= 1) { if (t < s) red[t] += red[t + s]; __syncthreads(); }
    if (t == 0) scal[0] = red[0];
    __syncthreads();
    red[t] = b_edge[t] * attn_w[2 * DIM + t];
    __syncthreads();
    for (int s = 64; s > 0; s >>= 1) { if (t < s) red[t] += red[t + s]; __syncthreads(); }
    if (t == 0) scal[1] = red[0] + attn_b[0];
}

// hs = src_feat @ W_src + b_src, fused s_score = hs . aw_s
// 64 rows/block, K-paneled LDS (W panel 16KB + A panel 9.2KB), 4x8 microtile/thread.
__global__ __launch_bounds__(256) void k_hs(const float* __restrict__ A,
                                            const float* __restrict__ W,
                                            const float* __restrict__ bias,
                                            const float* __restrict__ attn_w,
                                            float* __restrict__ hs,
                                            float* __restrict__ s_score) {
    __shared__ float Ws[32][128];   // k-panel of W, row-major
    __shared__ float As[64][36];    // A tile, stride 36 floats (16B-aligned, conflict-lite)

    const int t = threadIdx.x;
    const int r0 = blockIdx.x * 64;
    const int tc = t & 15;          // 16 col-groups x 8 cols
    const int tr4 = (t >> 4) * 4;   // 16 row-groups x 4 rows

    const int c0 = tc * 8;
    float acc[4][8];
    #pragma unroll
    for (int i = 0; i < 4; ++i)
        #pragma unroll
        for (int j = 0; j < 8; ++j) acc[i][j] = 0.f;

    for (int k0 = 0; k0 < DIM; k0 += 32) {
        // stage W panel: 4096 floats = 1024 float4
        #pragma unroll
        for (int i = 0; i < 4; ++i) {
            int f = t + 256 * i;
            int row = f >> 5, c4 = f & 31;
            float4 v = *reinterpret_cast<const float4*>(W + (size_t)(k0 + row) * DIM + c4 * 4);
            *reinterpret_cast<float4*>(&Ws[row][c4 * 4]) = v;
        }
        // stage A tile: 2048 floats = 512 float4
        #pragma unroll
        for (int i = 0; i < 2; ++i) {
            int f = t + 256 * i;
            int row = f >> 3, c4 = f & 7;
            int gr = r0 + row;
            float4 v = make_float4(0.f, 0.f, 0.f, 0.f);
            if (gr < NSRC) v = *reinterpret_cast<const float4*>(A + (size_t)gr * DIM + k0 + c4 * 4);
            *reinterpret_cast<float4*>(&As[row][c4 * 4]) = v;
        }
        __syncthreads();

        #pragma unroll 4
        for (int kk = 0; kk < 32; ++kk) {
            float a0 = As[tr4 + 0][kk];
            float a1 = As[tr4 + 1][kk];
            float a2 = As[tr4 + 2][kk];
            float a3 = As[tr4 + 3][kk];
            float4 w0 = *reinterpret_cast<const float4*>(&Ws[kk][c0]);
            float4 w1 = *reinterpret_cast<const float4*>(&Ws[kk][c0 + 4]);
            acc[0][0] += a0 * w0.x; acc[0][1] += a0 * w0.y; acc[0][2] += a0 * w0.z; acc[0][3] += a0 * w0.w;
            acc[0][4] += a0 * w1.x; acc[0][5] += a0 * w1.y; acc[0][6] += a0 * w1.z; acc[0][7] += a0 * w1.w;
            acc[1][0] += a1 * w0.x; acc[1][1] += a1 * w0.y; acc[1][2] += a1 * w0.z; acc[1][3] += a1 * w0.w;
            acc[1][4] += a1 * w1.x; acc[1][5] += a1 * w1.y; acc[1][6] += a1 * w1.z; acc[1][7] += a1 * w1.w;
            acc[2][0] += a2 * w0.x; acc[2][1] += a2 * w0.y; acc[2][2] += a2 * w0.z; acc[2][3] += a2 * w0.w;
            acc[2][4] += a2 * w1.x; acc[2][5] += a2 * w1.y; acc[2][6] += a2 * w1.z; acc[2][7] += a2 * w1.w;
            acc[3][0] += a3 * w0.x; acc[3][1] += a3 * w0.y; acc[3][2] += a3 * w0.z; acc[3][3] += a3 * w0.w;
            acc[3][4] += a3 * w1.x; acc[3][5] += a3 * w1.y; acc[3][6] += a3 * w1.z; acc[3][7] += a3 * w1.w;
        }
        __syncthreads();
    }

    // epilogue: + bias, store hs, fused s_score
    float4 b0 = *reinterpret_cast<const float4*>(bias + c0);
    float4 b1 = *reinterpret_cast<const float4*>(bias + c0 + 4);
    float4 aw0 = *reinterpret_cast<const float4*>(attn_w + c0);
    float4 aw1 = *reinterpret_cast<const float4*>(attn_w + c0 + 4);
    #pragma unroll
    for (int i = 0; i < 4; ++i) {
        int gr = r0 + tr4 + i;
        acc[i][0] += b0.x; acc[i][1] += b0.y; acc[i][2] += b0.z; acc[i][3] += b0.w;
        acc[i][4] += b1.x; acc[i][5] += b1.y; acc[i][6] += b1.z; acc[i][7] += b1.w;
        float p = acc[i][0] * aw0.x + acc[i][1] * aw0.y + acc[i][2] * aw0.z + acc[i][3] * aw0.w
                + acc[i][4] * aw1.x + acc[i][5] * aw1.y + acc[i][6] * aw1.z + acc[i][7] * aw1.w;
        p += __shfl_xor(p, 1);
        p += __shfl_xor(p, 2);
        p += __shfl_xor(p, 4);
        p += __shfl_xor(p, 8);
        if (gr < NSRC) {
            float4* o = reinterpret_cast<float4*>(hs + (size_t)gr * DIM + c0);
            o[0] = make_float4(acc[i][0], acc[i][1], acc[i][2], acc[i][3]);
            o[1] = make_float4(acc[i][4], acc[i][5], acc[i][6], acc[i][7]);
            if (tc == 0) s_score[gr] = p;
        }
    }
}

// d_score = dst_feat . wd_vec + scal[0]
__global__ __launch_bounds__(256) void k_dscore(const float* __restrict__ B,
                                                const float* __restrict__ wd_vec,
                                                const float* __restrict__ scal,
                                                float* __restrict__ d_score) {
    int t = threadIdx.x;
    int row = blockIdx.x * 32 + (t >> 3);
    int c0 = (t & 7) * 16;
    if (row >= NDST) return;
    const float4* x = reinterpret_cast<const float4*>(B + (size_t)row * DIM + c0);
    const float4* w = reinterpret_cast<const float4*>(wd_vec + c0);
    float p = 0.f;
    #pragma unroll
    for (int i = 0; i < 4; ++i) {
        float4 a = x[i], b = w[i];
        p += a.x * b.x + a.y * b.y + a.z * b.z + a.w * b.w;
    }
    p += __shfl_xor(p, 1);
    p += __shfl_xor(p, 2);
    p += __shfl_xor(p, 4);
    if ((t & 7) == 0) d_score[row] = p + scal[0];
}

// degree histogram over dst
__global__ void k_hist(const int* __restrict__ dst_idx, int* __restrict__ deg) {
    int e = blockIdx.x * blockDim.x + threadIdx.x;
    if (e < NEDGE) atomicAdd(&deg[dst_idx[e]], 1);
}

// single-block exclusive scan of deg -> off, cursor
__global__ __launch_bounds__(256) void k_scan(const int* __restrict__ deg,
                                              int* __restrict__ off,
                                              int* __restrict__ cursor) {
    __shared__ int part[256];
    int t = threadIdx.x;
    const int CH = (NDST + 255) / 256;
    int base = t * CH;
    int s = 0;
    for (int i = 0; i < CH; ++i) {
        int idx = base + i;
        if (idx < NDST) s += deg[idx];
    }
    part[t] = s;
    __syncthreads();
    for (int d = 1; d < 256; d <<= 1) {
        int v = (t >= d) ? part[t - d] : 0;
        __syncthreads();
        part[t] += v;
        __syncthreads();
    }
    int run = (t == 0) ? 0 : part[t - 1];
    for (int i = 0; i < CH; ++i) {
        int idx = base + i;
        if (idx < NDST) {
            off[idx] = run;
            cursor[idx] = run;
            run += deg[idx];
        }
    }
    if (t == 255) off[NDST] = run;
}

// per-edge logit + exp, scatter (src, w) into CSR slots
__global__ void k_fill(const float* __restrict__ ef, const int* __restrict__ src_idx,
                       const int* __restrict__ dst_idx, const float* __restrict__ s_score,
                       const float* __restrict__ d_score, const float* __restrict__ we_vec,
                       const float* __restrict__ scal,
                       int* __restrict__ cursor, int* __restrict__ ssrc,
                       float* __restrict__ sw) {
    int e = blockIdx.x * blockDim.x + threadIdx.x;
    if (e >= NEDGE) return;
    int s = src_idx[e], d = dst_idx[e];
    const float* er = ef + (size_t)e * EDIM;
    float a = scal[1];
    #pragma unroll
    for (int k = 0; k < EDIM; ++k) a += er[k] * we_vec[k];
    a += s_score[s] + d_score[d];
    // 0.05-scaled weights => |a| = O(3); exp without max-subtraction is exact
    // softmax algebraically and overflow-free here.
    float x = expf(a);
    int pos = atomicAdd(&cursor[d], 1);
    ssrc[pos] = s;
    sw[pos] = x;
}

// one wave per dst row: gather incoming edges, normalize in-register.
__global__ __launch_bounds__(256) void k_gather(const float* __restrict__ hs,
                                                const int* __restrict__ off,
                                                const int* __restrict__ ssrc,
                                                const float* __restrict__ sw,
                                                float* __restrict__ h_new) {
    int wid = (blockIdx.x * blockDim.x + threadIdx.x) >> 6;
    int lane = threadIdx.x & 63;
    if (wid >= NDST) return;
    int b = off[wid], e2 = off[wid + 1];
    float ax = 0.f, ay = 0.f, sum = 0.f;
    int j = b;
    for (; j + 2 <= e2; j += 2) {   // 2-way unroll: two gathers in flight
        int s0 = ssrc[j], s1 = ssrc[j + 1];
        float w0 = sw[j], w1 = sw[j + 1];
        float2 v0 = reinterpret_cast<const float2*>(hs + (size_t)s0 * DIM)[lane];
        float2 v1 = reinterpret_cast<const float2*>(hs + (size_t)s1 * DIM)[lane];
        sum += w0 + w1;
        ax += w0 * v0.x + w1 * v1.x;
        ay += w0 * v0.y + w1 * v1.y;
    }
    if (j < e2) {
        int s0 = ssrc[j];
        float w0 = sw[j];
        float2 v0 = reinterpret_cast<const float2*>(hs + (size_t)s0 * DIM)[lane];
        sum += w0;
        ax += w0 * v0.x;
        ay += w0 * v0.y;
    }
    float inv = (e2 > b) ? 1.f / sum : 0.f;  // zero-degree dst -> 0 row (matches ref)
    reinterpret_cast<float2*>(h_new + (size_t)wid * DIM)[lane] = make_float2(ax * inv, ay * inv);
}

// per-column sum / sumsq over h_new
__global__ __launch_bounds__(256) void k_bnstats(const float* __restrict__ h,
                                                 float* __restrict__ colsum,
                                                 float* __restrict__ colsq) {
    int col = threadIdx.x & 127;
    int rp = threadIdx.x >> 7;
    float s = 0.f, q = 0.f;
    for (int r = blockIdx.x * 2 + rp; r < NDST; r += gridDim.x * 2) {
        float x = h[(size_t)r * DIM + col];
        s += x;
        q += x * x;
    }
    __shared__ float ls[2][128], lq[2][128];
    ls[rp][col] = s;
    lq[rp][col] = q;
    __syncthreads();
    if (rp == 0) {
        atomicAdd(&colsum[col], ls[0][col] + ls[1][col]);
        atomicAdd(&colsq[col], lq[0][col] + lq[1][col]);
    }
}

// BN scale/shift computed per-thread in registers (col block fixed under grid-stride)
__global__ __launch_bounds__(256) void k_bnfinal(float* __restrict__ h,
                                                 const float* __restrict__ colsum,
                                                 const float* __restrict__ colsq,
                                                 const float* __restrict__ gamma,
                                                 const float* __restrict__ beta,
                                                 const float* __restrict__ alpha_p) {
    const size_t total4 = (size_t)NDST * DIM / 4;
    const float alpha = alpha_p[0];
    const float invN = 1.f / (float)NDST;
    const int c0 = (threadIdx.x & 31) * 4;  // stride is multiple of 32 -> col block fixed
    float sc[4], sh[4];
    #pragma unroll
    for (int k = 0; k < 4; ++k) {
        float mean = colsum[c0 + k] * invN;
        float var = colsq[c0 + k] * invN - mean * mean;
        float s = gamma[c0 + k] * rsqrtf(var + BN_EPS);
        sc[k] = s;
        sh[k] = beta[c0 + k] - mean * s;
    }
    size_t stride = (size_t)gridDim.x * blockDim.x;
    for (size_t i = blockIdx.x * blockDim.x + threadIdx.x; i < total4; i += stride) {
        float4 x = reinterpret_cast<float4*>(h)[i];
        float y0 = x.x * sc[0] + sh[0];
        float y1 = x.y * sc[1] + sh[1];
        float y2 = x.z * sc[2] + sh[2];
        float y3 = x.w * sc[3] + sh[3];
        float4 o;
        o.x = y0 >= 0.f ? y0 : alpha * y0;
        o.y = y1 >= 0.f ? y1 : alpha * y1;
        o.z = y2 >= 0.f ? y2 : alpha * y2;
        o.w = y3 >= 0.f ? y3 : alpha * y3;
        reinterpret_cast<float4*>(h)[i] = o;
    }
}

extern "C" void kernel_launch(void* const* d_in, const int* in_sizes, int n_in,
                              void* d_out, int out_size, void* d_ws, size_t ws_size,
                              hipStream_t stream) {
    const float* src_feat   = (const float*)d_in[0];
    const float* dst_feat   = (const float*)d_in[1];
    const float* edge_feats = (const float*)d_in[2];
    const int*   src_idx    = (const int*)d_in[3];
    const int*   dst_idx    = (const int*)d_in[4];
    const float* W_src      = (const float*)d_in[5];
    const float* b_src      = (const float*)d_in[6];
    const float* W_dst      = (const float*)d_in[7];
    const float* b_dst      = (const float*)d_in[8];
    const float* W_edge     = (const float*)d_in[9];
    const float* b_edge     = (const float*)d_in[10];
    const float* attn_w     = (const float*)d_in[11];
    const float* attn_b     = (const float*)d_in[12];
    const float* gamma      = (const float*)d_in[13];
    const float* beta       = (const float*)d_in[14];
    const float* alpha      = (const float*)d_in[15];

    float* ws      = (float*)d_ws;
    float* hs      = ws + OFF_HS;
    float* s_score = ws + OFF_SSCORE;
    float* d_score = ws + OFF_DSCORE;
    int*   deg     = (int*)(ws + OFF_DEG);
    int*   off     = (int*)(ws + OFF_OFFS);
    int*   cursor  = (int*)(ws + OFF_CURSOR);
    int*   ssrc    = (int*)(ws + OFF_SSRC);
    float* sw      = ws + OFF_SW;
    float* colsum  = ws + OFF_COLSUM;
    float* colsq   = ws + OFF_COLSQ;
    float* wd_vec  = ws + OFF_WDVEC;
    float* we_vec  = ws + OFF_WEVEC;
    float* scal    = ws + OFF_SCAL;

    float* h_new = (float*)d_out;

    hipMemsetAsync(deg, 0, NDST * sizeof(int), stream);
    hipMemsetAsync(colsum, 0, 256 * sizeof(float), stream);  // colsum+colsq contiguous

    k_prep<<<1, 128, 0, stream>>>(W_dst, b_dst, W_edge, b_edge, attn_w, attn_b,
                                  wd_vec, we_vec, scal);
    k_hs<<<(NSRC + 63) / 64, 256, 0, stream>>>(src_feat, W_src, b_src, attn_w, hs, s_score);
    k_dscore<<<(NDST + 31) / 32, 256, 0, stream>>>(dst_feat, wd_vec, scal, d_score);
    k_hist<<<(NEDGE + 255) / 256, 256, 0, stream>>>(dst_idx, deg);
    k_scan<<<1, 256, 0, stream>>>(deg, off, cursor);
    k_fill<<<(NEDGE + 255) / 256, 256, 0, stream>>>(edge_feats, src_idx, dst_idx,
                                                    s_score, d_score, we_vec, scal,
                                                    cursor, ssrc, sw);
    k_gather<<<(NDST * 64 + 255) / 256, 256, 0, stream>>>(hs, off, ssrc, sw, h_new);
    k_bnstats<<<512, 256, 0, stream>>>(h_new, colsum, colsq);
    k_bnfinal<<<1024, 256, 0, stream>>>(h_new, colsum, colsq, gamma, beta, alpha);
}

// Round 4
// 206.410 us; speedup vs baseline: 3.5327x; 1.6074x over previous
//
#include <hip/hip_runtime.h>
#include <cstddef>

#define NSRC 50000
#define NDST 50000
#define NEDGE 500000
#define DIM 128
#define EDIM 11
#define BN_EPS 1e-5f
#define SCAN_NBLK ((NDST + 255) / 256)   // 196

// ---------------- workspace layout (4B elems) ----------------
#define OFF_HS      0
#define OFF_SSCORE  (OFF_HS + (size_t)NSRC*DIM)
#define OFF_DSCORE  (OFF_SSCORE + NSRC)
#define OFF_DEG     (OFF_DSCORE + NDST)
#define OFF_OFFS    (OFF_DEG + NDST)
#define OFF_CURSOR  (OFF_OFFS + NDST + 1)
#define OFF_SSRC    (OFF_CURSOR + NDST)
#define OFF_SW      (OFF_SSRC + NEDGE)
#define OFF_COLSUM  (OFF_SW + NEDGE)
#define OFF_COLSQ   (OFF_COLSUM + 128)
#define OFF_WDVEC   (OFF_COLSQ + 128)
#define OFF_WEVEC   (OFF_WDVEC + 128)
#define OFF_SCAL    (OFF_WEVEC + 16)
#define OFF_PART    (OFF_SCAL + 4)

// wd_vec[k] = sum_d W_dst[k][d]*aw_d[d] ; we_vec[k] = sum_d W_edge[k][d]*aw_e[d]
// scal[0] = b_dst.aw_d ; scal[1] = b_edge.aw_e + attn_b
__global__ void k_prep(const float* __restrict__ W_dst, const float* __restrict__ b_dst,
                       const float* __restrict__ W_edge, const float* __restrict__ b_edge,
                       const float* __restrict__ attn_w, const float* __restrict__ attn_b,
                       float* __restrict__ wd_vec, float* __restrict__ we_vec,
                       float* __restrict__ scal) {
    int t = threadIdx.x;  // 128 threads
    float acc = 0.f;
    for (int d = 0; d < DIM; ++d) acc += W_dst[t * DIM + d] * attn_w[DIM + d];
    wd_vec[t] = acc;
    if (t < EDIM) {
        float e = 0.f;
        for (int d = 0; d < DIM; ++d) e += W_edge[t * DIM + d] * attn_w[2 * DIM + d];
        we_vec[t] = e;
    }
    __shared__ float red[128];
    red[t] = b_dst[t] * attn_w[DIM + t];
    __syncthreads();
    for (int s = 64; s > 0; s >>= 1) { if (t < s) red[t] += red[t + s]; __syncthreads(); }
    if (t == 0) scal[0] = red[0];
    __syncthreads();
    red[t] = b_edge[t] * attn_w[2 * DIM + t];
    __syncthreads();
    for (int s = 64; s > 0; s >>= 1) { if (t < s) red[t] += red[t + s]; __syncthreads(); }
    if (t == 0) scal[1] = red[0] + attn_b[0];
}

// hs = src_feat @ W_src + b_src, fused s_score = hs . aw_s
// 64 rows/block, K-paneled LDS, 4x8 microtile/thread.
__global__ __launch_bounds__(256) void k_hs(const float* __restrict__ A,
                                            const float* __restrict__ W,
                                            const float* __restrict__ bias,
                                            const float* __restrict__ attn_w,
                                            float* __restrict__ hs,
                                            float* __restrict__ s_score) {
    __shared__ float Ws[32][128];
    __shared__ float As[64][36];

    const int t = threadIdx.x;
    const int r0 = blockIdx.x * 64;
    const int tc = t & 15;
    const int tr4 = (t >> 4) * 4;

    const int c0 = tc * 8;
    float acc[4][8];
    #pragma unroll
    for (int i = 0; i < 4; ++i)
        #pragma unroll
        for (int j = 0; j < 8; ++j) acc[i][j] = 0.f;

    for (int k0 = 0; k0 < DIM; k0 += 32) {
        #pragma unroll
        for (int i = 0; i < 4; ++i) {
            int f = t + 256 * i;
            int row = f >> 5, c4 = f & 31;
            float4 v = *reinterpret_cast<const float4*>(W + (size_t)(k0 + row) * DIM + c4 * 4);
            *reinterpret_cast<float4*>(&Ws[row][c4 * 4]) = v;
        }
        #pragma unroll
        for (int i = 0; i < 2; ++i) {
            int f = t + 256 * i;
            int row = f >> 3, c4 = f & 7;
            int gr = r0 + row;
            float4 v = make_float4(0.f, 0.f, 0.f, 0.f);
            if (gr < NSRC) v = *reinterpret_cast<const float4*>(A + (size_t)gr * DIM + k0 + c4 * 4);
            *reinterpret_cast<float4*>(&As[row][c4 * 4]) = v;
        }
        __syncthreads();

        #pragma unroll 4
        for (int kk = 0; kk < 32; ++kk) {
            float a0 = As[tr4 + 0][kk];
            float a1 = As[tr4 + 1][kk];
            float a2 = As[tr4 + 2][kk];
            float a3 = As[tr4 + 3][kk];
            float4 w0 = *reinterpret_cast<const float4*>(&Ws[kk][c0]);
            float4 w1 = *reinterpret_cast<const float4*>(&Ws[kk][c0 + 4]);
            acc[0][0] += a0 * w0.x; acc[0][1] += a0 * w0.y; acc[0][2] += a0 * w0.z; acc[0][3] += a0 * w0.w;
            acc[0][4] += a0 * w1.x; acc[0][5] += a0 * w1.y; acc[0][6] += a0 * w1.z; acc[0][7] += a0 * w1.w;
            acc[1][0] += a1 * w0.x; acc[1][1] += a1 * w0.y; acc[1][2] += a1 * w0.z; acc[1][3] += a1 * w0.w;
            acc[1][4] += a1 * w1.x; acc[1][5] += a1 * w1.y; acc[1][6] += a1 * w1.z; acc[1][7] += a1 * w1.w;
            acc[2][0] += a2 * w0.x; acc[2][1] += a2 * w0.y; acc[2][2] += a2 * w0.z; acc[2][3] += a2 * w0.w;
            acc[2][4] += a2 * w1.x; acc[2][5] += a2 * w1.y; acc[2][6] += a2 * w1.z; acc[2][7] += a2 * w1.w;
            acc[3][0] += a3 * w0.x; acc[3][1] += a3 * w0.y; acc[3][2] += a3 * w0.z; acc[3][3] += a3 * w0.w;
            acc[3][4] += a3 * w1.x; acc[3][5] += a3 * w1.y; acc[3][6] += a3 * w1.z; acc[3][7] += a3 * w1.w;
        }
        __syncthreads();
    }

    float4 b0 = *reinterpret_cast<const float4*>(bias + c0);
    float4 b1 = *reinterpret_cast<const float4*>(bias + c0 + 4);
    float4 aw0 = *reinterpret_cast<const float4*>(attn_w + c0);
    float4 aw1 = *reinterpret_cast<const float4*>(attn_w + c0 + 4);
    #pragma unroll
    for (int i = 0; i < 4; ++i) {
        int gr = r0 + tr4 + i;
        acc[i][0] += b0.x; acc[i][1] += b0.y; acc[i][2] += b0.z; acc[i][3] += b0.w;
        acc[i][4] += b1.x; acc[i][5] += b1.y; acc[i][6] += b1.z; acc[i][7] += b1.w;
        float p = acc[i][0] * aw0.x + acc[i][1] * aw0.y + acc[i][2] * aw0.z + acc[i][3] * aw0.w
                + acc[i][4] * aw1.x + acc[i][5] * aw1.y + acc[i][6] * aw1.z + acc[i][7] * aw1.w;
        p += __shfl_xor(p, 1);
        p += __shfl_xor(p, 2);
        p += __shfl_xor(p, 4);
        p += __shfl_xor(p, 8);
        if (gr < NSRC) {
            float4* o = reinterpret_cast<float4*>(hs + (size_t)gr * DIM + c0);
            o[0] = make_float4(acc[i][0], acc[i][1], acc[i][2], acc[i][3]);
            o[1] = make_float4(acc[i][4], acc[i][5], acc[i][6], acc[i][7]);
            if (tc == 0) s_score[gr] = p;
        }
    }
}

// d_score = dst_feat . wd_vec + scal[0]
__global__ __launch_bounds__(256) void k_dscore(const float* __restrict__ B,
                                                const float* __restrict__ wd_vec,
                                                const float* __restrict__ scal,
                                                float* __restrict__ d_score) {
    int t = threadIdx.x;
    int row = blockIdx.x * 32 + (t >> 3);
    int c0 = (t & 7) * 16;
    if (row >= NDST) return;
    const float4* x = reinterpret_cast<const float4*>(B + (size_t)row * DIM + c0);
    const float4* w = reinterpret_cast<const float4*>(wd_vec + c0);
    float p = 0.f;
    #pragma unroll
    for (int i = 0; i < 4; ++i) {
        float4 a = x[i], b = w[i];
        p += a.x * b.x + a.y * b.y + a.z * b.z + a.w * b.w;
    }
    p += __shfl_xor(p, 1);
    p += __shfl_xor(p, 2);
    p += __shfl_xor(p, 4);
    if ((t & 7) == 0) d_score[row] = p + scal[0];
}

// degree histogram over dst
__global__ void k_hist(const int* __restrict__ dst_idx, int* __restrict__ deg) {
    int e = blockIdx.x * blockDim.x + threadIdx.x;
    if (e < NEDGE) atomicAdd(&deg[dst_idx[e]], 1);
}

// ---- parallel exclusive scan: A (per-chunk scan), B (scan block totals), C (add base)
__global__ __launch_bounds__(256) void k_scanA(const int* __restrict__ deg,
                                               int* __restrict__ off,
                                               int* __restrict__ partials) {
    __shared__ int tmp[256];
    int t = threadIdx.x;
    int i = blockIdx.x * 256 + t;
    int v = (i < NDST) ? deg[i] : 0;
    tmp[t] = v;
    __syncthreads();
    #pragma unroll
    for (int d = 1; d < 256; d <<= 1) {
        int u = (t >= d) ? tmp[t - d] : 0;
        __syncthreads();
        tmp[t] += u;
        __syncthreads();
    }
    if (i < NDST) off[i] = tmp[t] - v;          // local exclusive prefix
    if (t == 255) partials[blockIdx.x] = tmp[255];
}

__global__ __launch_bounds__(256) void k_scanB(int* __restrict__ partials) {
    __shared__ int tmp[256];
    int t = threadIdx.x;
    int v = (t < SCAN_NBLK) ? partials[t] : 0;
    tmp[t] = v;
    __syncthreads();
    #pragma unroll
    for (int d = 1; d < 256; d <<= 1) {
        int u = (t >= d) ? tmp[t - d] : 0;
        __syncthreads();
        tmp[t] += u;
        __syncthreads();
    }
    if (t < SCAN_NBLK) partials[t] = tmp[t] - v;  // exclusive base per block
}

__global__ __launch_bounds__(256) void k_scanC(int* __restrict__ off,
                                               int* __restrict__ cursor,
                                               const int* __restrict__ partials) {
    int t = threadIdx.x;
    int i = blockIdx.x * 256 + t;
    if (i < NDST) {
        int f = off[i] + partials[blockIdx.x];
        off[i] = f;
        cursor[i] = f;
    }
    if (i == 0) off[NDST] = NEDGE;
}

// per-edge logit + exp, scatter (src, w) into CSR slots
__global__ void k_fill(const float* __restrict__ ef, const int* __restrict__ src_idx,
                       const int* __restrict__ dst_idx, const float* __restrict__ s_score,
                       const float* __restrict__ d_score, const float* __restrict__ we_vec,
                       const float* __restrict__ scal,
                       int* __restrict__ cursor, int* __restrict__ ssrc,
                       float* __restrict__ sw) {
    int e = blockIdx.x * blockDim.x + threadIdx.x;
    if (e >= NEDGE) return;
    int s = src_idx[e], d = dst_idx[e];
    const float* er = ef + (size_t)e * EDIM;
    float a = scal[1];
    #pragma unroll
    for (int k = 0; k < EDIM; ++k) a += er[k] * we_vec[k];
    a += s_score[s] + d_score[d];
    // 0.05-scaled weights => |a| = O(3); exp without max-subtraction is exact
    // softmax algebraically and overflow-free here.
    float x = expf(a);
    int pos = atomicAdd(&cursor[d], 1);
    ssrc[pos] = s;
    sw[pos] = x;
}

// one wave per dst row: gather incoming edges, normalize in-register.
__global__ __launch_bounds__(256) void k_gather(const float* __restrict__ hs,
                                                const int* __restrict__ off,
                                                const int* __restrict__ ssrc,
                                                const float* __restrict__ sw,
                                                float* __restrict__ h_new) {
    int wid = (blockIdx.x * blockDim.x + threadIdx.x) >> 6;
    int lane = threadIdx.x & 63;
    if (wid >= NDST) return;
    int b = off[wid], e2 = off[wid + 1];
    float ax = 0.f, ay = 0.f, sum = 0.f;
    int j = b;
    for (; j + 2 <= e2; j += 2) {
        int s0 = ssrc[j], s1 = ssrc[j + 1];
        float w0 = sw[j], w1 = sw[j + 1];
        float2 v0 = reinterpret_cast<const float2*>(hs + (size_t)s0 * DIM)[lane];
        float2 v1 = reinterpret_cast<const float2*>(hs + (size_t)s1 * DIM)[lane];
        sum += w0 + w1;
        ax += w0 * v0.x + w1 * v1.x;
        ay += w0 * v0.y + w1 * v1.y;
    }
    if (j < e2) {
        int s0 = ssrc[j];
        float w0 = sw[j];
        float2 v0 = reinterpret_cast<const float2*>(hs + (size_t)s0 * DIM)[lane];
        sum += w0;
        ax += w0 * v0.x;
        ay += w0 * v0.y;
    }
    float inv = (e2 > b) ? 1.f / sum : 0.f;  // zero-degree dst -> 0 row (matches ref)
    reinterpret_cast<float2*>(h_new + (size_t)wid * DIM)[lane] = make_float2(ax * inv, ay * inv);
}

// per-column sum / sumsq over h_new
__global__ __launch_bounds__(256) void k_bnstats(const float* __restrict__ h,
                                                 float* __restrict__ colsum,
                                                 float* __restrict__ colsq) {
    int col = threadIdx.x & 127;
    int rp = threadIdx.x >> 7;
    float s = 0.f, q = 0.f;
    for (int r = blockIdx.x * 2 + rp; r < NDST; r += gridDim.x * 2) {
        float x = h[(size_t)r * DIM + col];
        s += x;
        q += x * x;
    }
    __shared__ float ls[2][128], lq[2][128];
    ls[rp][col] = s;
    lq[rp][col] = q;
    __syncthreads();
    if (rp == 0) {
        atomicAdd(&colsum[col], ls[0][col] + ls[1][col]);
        atomicAdd(&colsq[col], lq[0][col] + lq[1][col]);
    }
}

// BN scale/shift computed per-thread in registers (col block fixed under grid-stride)
__global__ __launch_bounds__(256) void k_bnfinal(float* __restrict__ h,
                                                 const float* __restrict__ colsum,
                                                 const float* __restrict__ colsq,
                                                 const float* __restrict__ gamma,
                                                 const float* __restrict__ beta,
                                                 const float* __restrict__ alpha_p) {
    const size_t total4 = (size_t)NDST * DIM / 4;
    const float alpha = alpha_p[0];
    const float invN = 1.f / (float)NDST;
    const int c0 = (threadIdx.x & 31) * 4;
    float sc[4], sh[4];
    #pragma unroll
    for (int k = 0; k < 4; ++k) {
        float mean = colsum[c0 + k] * invN;
        float var = colsq[c0 + k] * invN - mean * mean;
        float s = gamma[c0 + k] * rsqrtf(var + BN_EPS);
        sc[k] = s;
        sh[k] = beta[c0 + k] - mean * s;
    }
    size_t stride = (size_t)gridDim.x * blockDim.x;
    for (size_t i = blockIdx.x * blockDim.x + threadIdx.x; i < total4; i += stride) {
        float4 x = reinterpret_cast<float4*>(h)[i];
        float y0 = x.x * sc[0] + sh[0];
        float y1 = x.y * sc[1] + sh[1];
        float y2 = x.z * sc[2] + sh[2];
        float y3 = x.w * sc[3] + sh[3];
        float4 o;
        o.x = y0 >= 0.f ? y0 : alpha * y0;
        o.y = y1 >= 0.f ? y1 : alpha * y1;
        o.z = y2 >= 0.f ? y2 : alpha * y2;
        o.w = y3 >= 0.f ? y3 : alpha * y3;
        reinterpret_cast<float4*>(h)[i] = o;
    }
}

extern "C" void kernel_launch(void* const* d_in, const int* in_sizes, int n_in,
                              void* d_out, int out_size, void* d_ws, size_t ws_size,
                              hipStream_t stream) {
    const float* src_feat   = (const float*)d_in[0];
    const float* dst_feat   = (const float*)d_in[1];
    const float* edge_feats = (const float*)d_in[2];
    const int*   src_idx    = (const int*)d_in[3];
    const int*   dst_idx    = (const int*)d_in[4];
    const float* W_src      = (const float*)d_in[5];
    const float* b_src      = (const float*)d_in[6];
    const float* W_dst      = (const float*)d_in[7];
    const float* b_dst      = (const float*)d_in[8];
    const float* W_edge     = (const float*)d_in[9];
    const float* b_edge     = (const float*)d_in[10];
    const float* attn_w     = (const float*)d_in[11];
    const float* attn_b     = (const float*)d_in[12];
    const float* gamma      = (const float*)d_in[13];
    const float* beta       = (const float*)d_in[14];
    const float* alpha      = (const float*)d_in[15];

    float* ws      = (float*)d_ws;
    float* hs      = ws + OFF_HS;
    float* s_score = ws + OFF_SSCORE;
    float* d_score = ws + OFF_DSCORE;
    int*   deg     = (int*)(ws + OFF_DEG);
    int*   off     = (int*)(ws + OFF_OFFS);
    int*   cursor  = (int*)(ws + OFF_CURSOR);
    int*   ssrc    = (int*)(ws + OFF_SSRC);
    float* sw      = ws + OFF_SW;
    float* colsum  = ws + OFF_COLSUM;
    float* colsq   = ws + OFF_COLSQ;
    float* wd_vec  = ws + OFF_WDVEC;
    float* we_vec  = ws + OFF_WEVEC;
    float* scal    = ws + OFF_SCAL;
    int*   part    = (int*)(ws + OFF_PART);

    float* h_new = (float*)d_out;

    hipMemsetAsync(deg, 0, NDST * sizeof(int), stream);
    hipMemsetAsync(colsum, 0, 256 * sizeof(float), stream);  // colsum+colsq contiguous

    k_prep<<<1, 128, 0, stream>>>(W_dst, b_dst, W_edge, b_edge, attn_w, attn_b,
                                  wd_vec, we_vec, scal);
    k_hs<<<(NSRC + 63) / 64, 256, 0, stream>>>(src_feat, W_src, b_src, attn_w, hs, s_score);
    k_dscore<<<(NDST + 31) / 32, 256, 0, stream>>>(dst_feat, wd_vec, scal, d_score);
    k_hist<<<(NEDGE + 255) / 256, 256, 0, stream>>>(dst_idx, deg);
    k_scanA<<<SCAN_NBLK, 256, 0, stream>>>(deg, off, part);
    k_scanB<<<1, 256, 0, stream>>>(part);
    k_scanC<<<SCAN_NBLK, 256, 0, stream>>>(off, cursor, part);
    k_fill<<<(NEDGE + 255) / 256, 256, 0, stream>>>(edge_feats, src_idx, dst_idx,
                                                    s_score, d_score, we_vec, scal,
                                                    cursor, ssrc, sw);
    k_gather<<<(NDST * 64 + 255) / 256, 256, 0, stream>>>(hs, off, ssrc, sw, h_new);
    k_bnstats<<<512, 256, 0, stream>>>(h_new, colsum, colsq);
    k_bnfinal<<<1024, 256, 0, stream>>>(h_new, colsum, colsq, gamma, beta, alpha);
}

// Round 5
// 200.581 us; speedup vs baseline: 3.6354x; 1.0291x over previous
//
#include <hip/hip_runtime.h>
#include <cstddef>

#define NSRC 50000
#define NDST 50000
#define NEDGE 500000
#define DIM 128
#define EDIM 11
#define BN_EPS 1e-5f
#define SCAN_NBLK ((NDST + 255) / 256)   // 196

// ---------------- workspace layout (4B elems) ----------------
#define OFF_HS      0
#define OFF_SSCORE  (OFF_HS + (size_t)NSRC*DIM)
#define OFF_DSCORE  (OFF_SSCORE + NSRC)
#define OFF_DEG     (OFF_DSCORE + NDST)
#define OFF_OFFS    (OFF_DEG + NDST)
#define OFF_CURSOR  (OFF_OFFS + NDST + 1)
#define OFF_SSRC    (OFF_CURSOR + NDST)
#define OFF_SW      (OFF_SSRC + NEDGE)
#define OFF_COLSUM  (OFF_SW + NEDGE)
#define OFF_COLSQ   (OFF_COLSUM + 128)
#define OFF_WDVEC   (OFF_COLSQ + 128)
#define OFF_WEVEC   (OFF_WDVEC + 128)
#define OFF_SCAL    (OFF_WEVEC + 16)
#define OFF_PART    (OFF_SCAL + 4)

// wd_vec[k] = sum_d W_dst[k][d]*aw_d[d] ; we_vec[k] = sum_d W_edge[k][d]*aw_e[d]
// scal[0] = b_dst.aw_d ; scal[1] = b_edge.aw_e + attn_b
__global__ void k_prep(const float* __restrict__ W_dst, const float* __restrict__ b_dst,
                       const float* __restrict__ W_edge, const float* __restrict__ b_edge,
                       const float* __restrict__ attn_w, const float* __restrict__ attn_b,
                       float* __restrict__ wd_vec, float* __restrict__ we_vec,
                       float* __restrict__ scal) {
    int t = threadIdx.x;  // 128 threads
    float acc = 0.f;
    for (int d = 0; d < DIM; ++d) acc += W_dst[t * DIM + d] * attn_w[DIM + d];
    wd_vec[t] = acc;
    if (t < EDIM) {
        float e = 0.f;
        for (int d = 0; d < DIM; ++d) e += W_edge[t * DIM + d] * attn_w[2 * DIM + d];
        we_vec[t] = e;
    }
    __shared__ float red[128];
    red[t] = b_dst[t] * attn_w[DIM + t];
    __syncthreads();
    for (int s = 64; s > 0; s >>= 1) { if (t < s) red[t] += red[t + s]; __syncthreads(); }
    if (t == 0) scal[0] = red[0];
    __syncthreads();
    red[t] = b_edge[t] * attn_w[2 * DIM + t];
    __syncthreads();
    for (int s = 64; s > 0; s >>= 1) { if (t < s) red[t] += red[t + s]; __syncthreads(); }
    if (t == 0) scal[1] = red[0] + attn_b[0];
}

// hs = src_feat @ W_src + b_src, fused s_score = hs . aw_s
// 64 rows/block, K-paneled LDS, 4x8 microtile/thread.
__global__ __launch_bounds__(256) void k_hs(const float* __restrict__ A,
                                            const float* __restrict__ W,
                                            const float* __restrict__ bias,
                                            const float* __restrict__ attn_w,
                                            float* __restrict__ hs,
                                            float* __restrict__ s_score) {
    __shared__ float Ws[32][128];
    __shared__ float As[64][36];

    const int t = threadIdx.x;
    const int r0 = blockIdx.x * 64;
    const int tc = t & 15;
    const int tr4 = (t >> 4) * 4;

    const int c0 = tc * 8;
    float acc[4][8];
    #pragma unroll
    for (int i = 0; i < 4; ++i)
        #pragma unroll
        for (int j = 0; j < 8; ++j) acc[i][j] = 0.f;

    for (int k0 = 0; k0 < DIM; k0 += 32) {
        #pragma unroll
        for (int i = 0; i < 4; ++i) {
            int f = t + 256 * i;
            int row = f >> 5, c4 = f & 31;
            float4 v = *reinterpret_cast<const float4*>(W + (size_t)(k0 + row) * DIM + c4 * 4);
            *reinterpret_cast<float4*>(&Ws[row][c4 * 4]) = v;
        }
        #pragma unroll
        for (int i = 0; i < 2; ++i) {
            int f = t + 256 * i;
            int row = f >> 3, c4 = f & 7;
            int gr = r0 + row;
            float4 v = make_float4(0.f, 0.f, 0.f, 0.f);
            if (gr < NSRC) v = *reinterpret_cast<const float4*>(A + (size_t)gr * DIM + k0 + c4 * 4);
            *reinterpret_cast<float4*>(&As[row][c4 * 4]) = v;
        }
        __syncthreads();

        #pragma unroll 4
        for (int kk = 0; kk < 32; ++kk) {
            float a0 = As[tr4 + 0][kk];
            float a1 = As[tr4 + 1][kk];
            float a2 = As[tr4 + 2][kk];
            float a3 = As[tr4 + 3][kk];
            float4 w0 = *reinterpret_cast<const float4*>(&Ws[kk][c0]);
            float4 w1 = *reinterpret_cast<const float4*>(&Ws[kk][c0 + 4]);
            acc[0][0] += a0 * w0.x; acc[0][1] += a0 * w0.y; acc[0][2] += a0 * w0.z; acc[0][3] += a0 * w0.w;
            acc[0][4] += a0 * w1.x; acc[0][5] += a0 * w1.y; acc[0][6] += a0 * w1.z; acc[0][7] += a0 * w1.w;
            acc[1][0] += a1 * w0.x; acc[1][1] += a1 * w0.y; acc[1][2] += a1 * w0.z; acc[1][3] += a1 * w0.w;
            acc[1][4] += a1 * w1.x; acc[1][5] += a1 * w1.y; acc[1][6] += a1 * w1.z; acc[1][7] += a1 * w1.w;
            acc[2][0] += a2 * w0.x; acc[2][1] += a2 * w0.y; acc[2][2] += a2 * w0.z; acc[2][3] += a2 * w0.w;
            acc[2][4] += a2 * w1.x; acc[2][5] += a2 * w1.y; acc[2][6] += a2 * w1.z; acc[2][7] += a2 * w1.w;
            acc[3][0] += a3 * w0.x; acc[3][1] += a3 * w0.y; acc[3][2] += a3 * w0.z; acc[3][3] += a3 * w0.w;
            acc[3][4] += a3 * w1.x; acc[3][5] += a3 * w1.y; acc[3][6] += a3 * w1.z; acc[3][7] += a3 * w1.w;
        }
        __syncthreads();
    }

    float4 b0 = *reinterpret_cast<const float4*>(bias + c0);
    float4 b1 = *reinterpret_cast<const float4*>(bias + c0 + 4);
    float4 aw0 = *reinterpret_cast<const float4*>(attn_w + c0);
    float4 aw1 = *reinterpret_cast<const float4*>(attn_w + c0 + 4);
    #pragma unroll
    for (int i = 0; i < 4; ++i) {
        int gr = r0 + tr4 + i;
        acc[i][0] += b0.x; acc[i][1] += b0.y; acc[i][2] += b0.z; acc[i][3] += b0.w;
        acc[i][4] += b1.x; acc[i][5] += b1.y; acc[i][6] += b1.z; acc[i][7] += b1.w;
        float p = acc[i][0] * aw0.x + acc[i][1] * aw0.y + acc[i][2] * aw0.z + acc[i][3] * aw0.w
                + acc[i][4] * aw1.x + acc[i][5] * aw1.y + acc[i][6] * aw1.z + acc[i][7] * aw1.w;
        p += __shfl_xor(p, 1);
        p += __shfl_xor(p, 2);
        p += __shfl_xor(p, 4);
        p += __shfl_xor(p, 8);
        if (gr < NSRC) {
            float4* o = reinterpret_cast<float4*>(hs + (size_t)gr * DIM + c0);
            o[0] = make_float4(acc[i][0], acc[i][1], acc[i][2], acc[i][3]);
            o[1] = make_float4(acc[i][4], acc[i][5], acc[i][6], acc[i][7]);
            if (tc == 0) s_score[gr] = p;
        }
    }
}

// d_score = dst_feat . wd_vec + scal[0]
__global__ __launch_bounds__(256) void k_dscore(const float* __restrict__ B,
                                                const float* __restrict__ wd_vec,
                                                const float* __restrict__ scal,
                                                float* __restrict__ d_score) {
    int t = threadIdx.x;
    int row = blockIdx.x * 32 + (t >> 3);
    int c0 = (t & 7) * 16;
    if (row >= NDST) return;
    const float4* x = reinterpret_cast<const float4*>(B + (size_t)row * DIM + c0);
    const float4* w = reinterpret_cast<const float4*>(wd_vec + c0);
    float p = 0.f;
    #pragma unroll
    for (int i = 0; i < 4; ++i) {
        float4 a = x[i], b = w[i];
        p += a.x * b.x + a.y * b.y + a.z * b.z + a.w * b.w;
    }
    p += __shfl_xor(p, 1);
    p += __shfl_xor(p, 2);
    p += __shfl_xor(p, 4);
    if ((t & 7) == 0) d_score[row] = p + scal[0];
}

// degree histogram over dst
__global__ void k_hist(const int* __restrict__ dst_idx, int* __restrict__ deg) {
    int e = blockIdx.x * blockDim.x + threadIdx.x;
    if (e < NEDGE) atomicAdd(&deg[dst_idx[e]], 1);
}

// ---- parallel exclusive scan: A (per-chunk scan), B (scan block totals), C (add base)
__global__ __launch_bounds__(256) void k_scanA(const int* __restrict__ deg,
                                               int* __restrict__ off,
                                               int* __restrict__ partials) {
    __shared__ int tmp[256];
    int t = threadIdx.x;
    int i = blockIdx.x * 256 + t;
    int v = (i < NDST) ? deg[i] : 0;
    tmp[t] = v;
    __syncthreads();
    #pragma unroll
    for (int d = 1; d < 256; d <<= 1) {
        int u = (t >= d) ? tmp[t - d] : 0;
        __syncthreads();
        tmp[t] += u;
        __syncthreads();
    }
    if (i < NDST) off[i] = tmp[t] - v;          // local exclusive prefix
    if (t == 255) partials[blockIdx.x] = tmp[255];
}

__global__ __launch_bounds__(256) void k_scanB(int* __restrict__ partials) {
    __shared__ int tmp[256];
    int t = threadIdx.x;
    int v = (t < SCAN_NBLK) ? partials[t] : 0;
    tmp[t] = v;
    __syncthreads();
    #pragma unroll
    for (int d = 1; d < 256; d <<= 1) {
        int u = (t >= d) ? tmp[t - d] : 0;
        __syncthreads();
        tmp[t] += u;
        __syncthreads();
    }
    if (t < SCAN_NBLK) partials[t] = tmp[t] - v;  // exclusive base per block
}

__global__ __launch_bounds__(256) void k_scanC(int* __restrict__ off,
                                               int* __restrict__ cursor,
                                               const int* __restrict__ partials) {
    int t = threadIdx.x;
    int i = blockIdx.x * 256 + t;
    if (i < NDST) {
        int f = off[i] + partials[blockIdx.x];
        off[i] = f;
        cursor[i] = f;
    }
    if (i == 0) off[NDST] = NEDGE;
}

// per-edge logit + exp, scatter (src, w) into CSR slots
__global__ void k_fill(const float* __restrict__ ef, const int* __restrict__ src_idx,
                       const int* __restrict__ dst_idx, const float* __restrict__ s_score,
                       const float* __restrict__ d_score, const float* __restrict__ we_vec,
                       const float* __restrict__ scal,
                       int* __restrict__ cursor, int* __restrict__ ssrc,
                       float* __restrict__ sw) {
    int e = blockIdx.x * blockDim.x + threadIdx.x;
    if (e >= NEDGE) return;
    int s = src_idx[e], d = dst_idx[e];
    const float* er = ef + (size_t)e * EDIM;
    float a = scal[1];
    #pragma unroll
    for (int k = 0; k < EDIM; ++k) a += er[k] * we_vec[k];
    a += s_score[s] + d_score[d];
    // 0.05-scaled weights => |a| = O(3); exp without max-subtraction is exact
    // softmax algebraically and overflow-free here.
    float x = expf(a);
    int pos = atomicAdd(&cursor[d], 1);
    ssrc[pos] = s;
    sw[pos] = x;
}

// one wave per dst row. Batch edge (src,w) into registers (one coalesced load
// per 64 edges), broadcast via shfl -> all hs gathers issue independently.
__global__ __launch_bounds__(256) void k_gather(const float* __restrict__ hs,
                                                const int* __restrict__ off,
                                                const int* __restrict__ ssrc,
                                                const float* __restrict__ sw,
                                                float* __restrict__ h_new) {
    int wid = (blockIdx.x * blockDim.x + threadIdx.x) >> 6;
    int lane = threadIdx.x & 63;
    if (wid >= NDST) return;
    int b = off[wid], e2 = off[wid + 1];
    int deg = e2 - b;
    float ax = 0.f, ay = 0.f, wsum = 0.f;

    for (int base = 0; base < deg; base += 64) {
        int cnt = min(deg - base, 64);
        int myS = 0;
        float myW = 0.f;
        if (lane < cnt) {
            myS = ssrc[b + base + lane];
            myW = sw[b + base + lane];
        }
        wsum += myW;

        int j = 0;
        for (; j + 4 <= cnt; j += 4) {
            int s0 = __shfl(myS, j + 0), s1 = __shfl(myS, j + 1);
            int s2 = __shfl(myS, j + 2), s3 = __shfl(myS, j + 3);
            float w0 = __shfl(myW, j + 0), w1 = __shfl(myW, j + 1);
            float w2 = __shfl(myW, j + 2), w3 = __shfl(myW, j + 3);
            float2 v0 = reinterpret_cast<const float2*>(hs + (size_t)s0 * DIM)[lane];
            float2 v1 = reinterpret_cast<const float2*>(hs + (size_t)s1 * DIM)[lane];
            float2 v2 = reinterpret_cast<const float2*>(hs + (size_t)s2 * DIM)[lane];
            float2 v3 = reinterpret_cast<const float2*>(hs + (size_t)s3 * DIM)[lane];
            ax += w0 * v0.x + w1 * v1.x + w2 * v2.x + w3 * v3.x;
            ay += w0 * v0.y + w1 * v1.y + w2 * v2.y + w3 * v3.y;
        }
        for (; j < cnt; ++j) {
            int s0 = __shfl(myS, j);
            float w0 = __shfl(myW, j);
            float2 v0 = reinterpret_cast<const float2*>(hs + (size_t)s0 * DIM)[lane];
            ax += w0 * v0.x;
            ay += w0 * v0.y;
        }
    }

    // butterfly-reduce wsum across the wave (all lanes get total)
    #pragma unroll
    for (int m = 1; m < 64; m <<= 1) wsum += __shfl_xor(wsum, m);

    float inv = (deg > 0) ? 1.f / wsum : 0.f;  // zero-degree dst -> 0 row (matches ref)
    reinterpret_cast<float2*>(h_new + (size_t)wid * DIM)[lane] = make_float2(ax * inv, ay * inv);
}

// per-column sum / sumsq over h_new
__global__ __launch_bounds__(256) void k_bnstats(const float* __restrict__ h,
                                                 float* __restrict__ colsum,
                                                 float* __restrict__ colsq) {
    int col = threadIdx.x & 127;
    int rp = threadIdx.x >> 7;
    float s = 0.f, q = 0.f;
    for (int r = blockIdx.x * 2 + rp; r < NDST; r += gridDim.x * 2) {
        float x = h[(size_t)r * DIM + col];
        s += x;
        q += x * x;
    }
    __shared__ float ls[2][128], lq[2][128];
    ls[rp][col] = s;
    lq[rp][col] = q;
    __syncthreads();
    if (rp == 0) {
        atomicAdd(&colsum[col], ls[0][col] + ls[1][col]);
        atomicAdd(&colsq[col], lq[0][col] + lq[1][col]);
    }
}

// BN scale/shift computed per-thread in registers (col block fixed under grid-stride)
__global__ __launch_bounds__(256) void k_bnfinal(float* __restrict__ h,
                                                 const float* __restrict__ colsum,
                                                 const float* __restrict__ colsq,
                                                 const float* __restrict__ gamma,
                                                 const float* __restrict__ beta,
                                                 const float* __restrict__ alpha_p) {
    const size_t total4 = (size_t)NDST * DIM / 4;
    const float alpha = alpha_p[0];
    const float invN = 1.f / (float)NDST;
    const int c0 = (threadIdx.x & 31) * 4;
    float sc[4], sh[4];
    #pragma unroll
    for (int k = 0; k < 4; ++k) {
        float mean = colsum[c0 + k] * invN;
        float var = colsq[c0 + k] * invN - mean * mean;
        float s = gamma[c0 + k] * rsqrtf(var + BN_EPS);
        sc[k] = s;
        sh[k] = beta[c0 + k] - mean * s;
    }
    size_t stride = (size_t)gridDim.x * blockDim.x;
    for (size_t i = blockIdx.x * blockDim.x + threadIdx.x; i < total4; i += stride) {
        float4 x = reinterpret_cast<float4*>(h)[i];
        float y0 = x.x * sc[0] + sh[0];
        float y1 = x.y * sc[1] + sh[1];
        float y2 = x.z * sc[2] + sh[2];
        float y3 = x.w * sc[3] + sh[3];
        float4 o;
        o.x = y0 >= 0.f ? y0 : alpha * y0;
        o.y = y1 >= 0.f ? y1 : alpha * y1;
        o.z = y2 >= 0.f ? y2 : alpha * y2;
        o.w = y3 >= 0.f ? y3 : alpha * y3;
        reinterpret_cast<float4*>(h)[i] = o;
    }
}

extern "C" void kernel_launch(void* const* d_in, const int* in_sizes, int n_in,
                              void* d_out, int out_size, void* d_ws, size_t ws_size,
                              hipStream_t stream) {
    const float* src_feat   = (const float*)d_in[0];
    const float* dst_feat   = (const float*)d_in[1];
    const float* edge_feats = (const float*)d_in[2];
    const int*   src_idx    = (const int*)d_in[3];
    const int*   dst_idx    = (const int*)d_in[4];
    const float* W_src      = (const float*)d_in[5];
    const float* b_src      = (const float*)d_in[6];
    const float* W_dst      = (const float*)d_in[7];
    const float* b_dst      = (const float*)d_in[8];
    const float* W_edge     = (const float*)d_in[9];
    const float* b_edge     = (const float*)d_in[10];
    const float* attn_w     = (const float*)d_in[11];
    const float* attn_b     = (const float*)d_in[12];
    const float* gamma      = (const float*)d_in[13];
    const float* beta       = (const float*)d_in[14];
    const float* alpha      = (const float*)d_in[15];

    float* ws      = (float*)d_ws;
    float* hs      = ws + OFF_HS;
    float* s_score = ws + OFF_SSCORE;
    float* d_score = ws + OFF_DSCORE;
    int*   deg     = (int*)(ws + OFF_DEG);
    int*   off     = (int*)(ws + OFF_OFFS);
    int*   cursor  = (int*)(ws + OFF_CURSOR);
    int*   ssrc    = (int*)(ws + OFF_SSRC);
    float* sw      = ws + OFF_SW;
    float* colsum  = ws + OFF_COLSUM;
    float* colsq   = ws + OFF_COLSQ;
    float* wd_vec  = ws + OFF_WDVEC;
    float* we_vec  = ws + OFF_WEVEC;
    float* scal    = ws + OFF_SCAL;
    int*   part    = (int*)(ws + OFF_PART);

    float* h_new = (float*)d_out;

    hipMemsetAsync(deg, 0, NDST * sizeof(int), stream);
    hipMemsetAsync(colsum, 0, 256 * sizeof(float), stream);  // colsum+colsq contiguous

    k_prep<<<1, 128, 0, stream>>>(W_dst, b_dst, W_edge, b_edge, attn_w, attn_b,
                                  wd_vec, we_vec, scal);
    k_hs<<<(NSRC + 63) / 64, 256, 0, stream>>>(src_feat, W_src, b_src, attn_w, hs, s_score);
    k_dscore<<<(NDST + 31) / 32, 256, 0, stream>>>(dst_feat, wd_vec, scal, d_score);
    k_hist<<<(NEDGE + 255) / 256, 256, 0, stream>>>(dst_idx, deg);
    k_scanA<<<SCAN_NBLK, 256, 0, stream>>>(deg, off, part);
    k_scanB<<<1, 256, 0, stream>>>(part);
    k_scanC<<<SCAN_NBLK, 256, 0, stream>>>(off, cursor, part);
    k_fill<<<(NEDGE + 255) / 256, 256, 0, stream>>>(edge_feats, src_idx, dst_idx,
                                                    s_score, d_score, we_vec, scal,
                                                    cursor, ssrc, sw);
    k_gather<<<(NDST * 64 + 255) / 256, 256, 0, stream>>>(hs, off, ssrc, sw, h_new);
    k_bnstats<<<512, 256, 0, stream>>>(h_new, colsum, colsq);
    k_bnfinal<<<1024, 256, 0, stream>>>(h_new, colsum, colsq, gamma, beta, alpha);
}

// Round 6
// 166.074 us; speedup vs baseline: 4.3907x; 1.2078x over previous
//
#include <hip/hip_runtime.h>
#include <cstddef>

#define NSRC 50000
#define NDST 50000
#define NEDGE 500000
#define DIM 128
#define EDIM 11
#define BN_EPS 1e-5f
#define SCAN_NBLK ((NDST + 255) / 256)   // 196

#define HS_BLOCKS ((NSRC + 63) / 64)     // 782
#define DS_BLOCKS ((NDST + 31) / 32)     // 1563
#define ED_BLOCKS ((NEDGE + 1023) / 1024) // 489

// ---------------- workspace layout (4B elems) ----------------
#define OFF_HS      0
#define OFF_SSCORE  (OFF_HS + (size_t)NSRC*DIM)
#define OFF_DSCORE  (OFF_SSCORE + NSRC)
#define OFF_EE      (OFF_DSCORE + NDST)
#define OFF_DEG     (OFF_EE + NEDGE)
#define OFF_COLSUM  (OFF_DEG + NDST)          // deg..colsq contiguous: one memset
#define OFF_COLSQ   (OFF_COLSUM + 128)
#define OFF_OFFS    (OFF_COLSQ + 128)
#define OFF_CURSOR  (OFF_OFFS + NDST + 2)     // +2 keeps OFF_PAIRS even (8B aligned)
#define OFF_PAIRS   (OFF_CURSOR + NDST)       // int2[NEDGE]
#define OFF_WDVEC   (OFF_PAIRS + 2*(size_t)NEDGE)
#define OFF_WEVEC   (OFF_WDVEC + 128)
#define OFF_SCAL    (OFF_WEVEC + 16)
#define OFF_PART    (OFF_SCAL + 4)

// wd_vec[k] = sum_d W_dst[k][d]*aw_d[d] ; we_vec[k] = sum_d W_edge[k][d]*aw_e[d]
// scal[0] = b_dst.aw_d ; scal[1] = b_edge.aw_e + attn_b
__global__ void k_prep(const float* __restrict__ W_dst, const float* __restrict__ b_dst,
                       const float* __restrict__ W_edge, const float* __restrict__ b_edge,
                       const float* __restrict__ attn_w, const float* __restrict__ attn_b,
                       float* __restrict__ wd_vec, float* __restrict__ we_vec,
                       float* __restrict__ scal) {
    int t = threadIdx.x;  // 128 threads
    float acc = 0.f;
    for (int d = 0; d < DIM; ++d) acc += W_dst[t * DIM + d] * attn_w[DIM + d];
    wd_vec[t] = acc;
    if (t < EDIM) {
        float e = 0.f;
        for (int d = 0; d < DIM; ++d) e += W_edge[t * DIM + d] * attn_w[2 * DIM + d];
        we_vec[t] = e;
    }
    __shared__ float red[128];
    red[t] = b_dst[t] * attn_w[DIM + t];
    __syncthreads();
    for (int s = 64; s > 0; s >>= 1) { if (t < s) red[t] += red[t + s]; __syncthreads(); }
    if (t == 0) scal[0] = red[0];
    __syncthreads();
    red[t] = b_edge[t] * attn_w[2 * DIM + t];
    __syncthreads();
    for (int s = 64; s > 0; s >>= 1) { if (t < s) red[t] += red[t + s]; __syncthreads(); }
    if (t == 0) scal[1] = red[0] + attn_b[0];
}

// Fused: role 0 = hs GEMM (+s_score), role 1 = d_score, role 2 = edge partial
// logit ee[e] + degree histogram. Roles run CONCURRENTLY (one grid) so the
// latency-bound edge/hist work hides under the compute-bound GEMM.
__global__ __launch_bounds__(256) void k_fused(const float* __restrict__ A,
                                               const float* __restrict__ W,
                                               const float* __restrict__ bias,
                                               const float* __restrict__ attn_w,
                                               const float* __restrict__ B,
                                               const float* __restrict__ ef,
                                               const int* __restrict__ dst_idx,
                                               const float* __restrict__ wd_vec,
                                               const float* __restrict__ we_vec,
                                               const float* __restrict__ scal,
                                               float* __restrict__ hs,
                                               float* __restrict__ s_score,
                                               float* __restrict__ d_score,
                                               float* __restrict__ ee,
                                               int* __restrict__ deg) {
    __shared__ float Ws[32][128];
    __shared__ float As[64][36];
    const int bid = blockIdx.x;
    const int t = threadIdx.x;

    if (bid < HS_BLOCKS) {
        // ---- role 0: hs = A @ W + bias, fused s_score ----
        const int r0 = bid * 64;
        const int tc = t & 15;
        const int tr4 = (t >> 4) * 4;
        const int c0 = tc * 8;
        float acc[4][8];
        #pragma unroll
        for (int i = 0; i < 4; ++i)
            #pragma unroll
            for (int j = 0; j < 8; ++j) acc[i][j] = 0.f;

        for (int k0 = 0; k0 < DIM; k0 += 32) {
            #pragma unroll
            for (int i = 0; i < 4; ++i) {
                int f = t + 256 * i;
                int row = f >> 5, c4 = f & 31;
                float4 v = *reinterpret_cast<const float4*>(W + (size_t)(k0 + row) * DIM + c4 * 4);
                *reinterpret_cast<float4*>(&Ws[row][c4 * 4]) = v;
            }
            #pragma unroll
            for (int i = 0; i < 2; ++i) {
                int f = t + 256 * i;
                int row = f >> 3, c4 = f & 7;
                int gr = r0 + row;
                float4 v = make_float4(0.f, 0.f, 0.f, 0.f);
                if (gr < NSRC) v = *reinterpret_cast<const float4*>(A + (size_t)gr * DIM + k0 + c4 * 4);
                *reinterpret_cast<float4*>(&As[row][c4 * 4]) = v;
            }
            __syncthreads();

            #pragma unroll 4
            for (int kk = 0; kk < 32; ++kk) {
                float a0 = As[tr4 + 0][kk];
                float a1 = As[tr4 + 1][kk];
                float a2 = As[tr4 + 2][kk];
                float a3 = As[tr4 + 3][kk];
                float4 w0 = *reinterpret_cast<const float4*>(&Ws[kk][c0]);
                float4 w1 = *reinterpret_cast<const float4*>(&Ws[kk][c0 + 4]);
                acc[0][0] += a0 * w0.x; acc[0][1] += a0 * w0.y; acc[0][2] += a0 * w0.z; acc[0][3] += a0 * w0.w;
                acc[0][4] += a0 * w1.x; acc[0][5] += a0 * w1.y; acc[0][6] += a0 * w1.z; acc[0][7] += a0 * w1.w;
                acc[1][0] += a1 * w0.x; acc[1][1] += a1 * w0.y; acc[1][2] += a1 * w0.z; acc[1][3] += a1 * w0.w;
                acc[1][4] += a1 * w1.x; acc[1][5] += a1 * w1.y; acc[1][6] += a1 * w1.z; acc[1][7] += a1 * w1.w;
                acc[2][0] += a2 * w0.x; acc[2][1] += a2 * w0.y; acc[2][2] += a2 * w0.z; acc[2][3] += a2 * w0.w;
                acc[2][4] += a2 * w1.x; acc[2][5] += a2 * w1.y; acc[2][6] += a2 * w1.z; acc[2][7] += a2 * w1.w;
                acc[3][0] += a3 * w0.x; acc[3][1] += a3 * w0.y; acc[3][2] += a3 * w0.z; acc[3][3] += a3 * w0.w;
                acc[3][4] += a3 * w1.x; acc[3][5] += a3 * w1.y; acc[3][6] += a3 * w1.z; acc[3][7] += a3 * w1.w;
            }
            __syncthreads();
        }

        float4 b0 = *reinterpret_cast<const float4*>(bias + c0);
        float4 b1 = *reinterpret_cast<const float4*>(bias + c0 + 4);
        float4 aw0 = *reinterpret_cast<const float4*>(attn_w + c0);
        float4 aw1 = *reinterpret_cast<const float4*>(attn_w + c0 + 4);
        #pragma unroll
        for (int i = 0; i < 4; ++i) {
            int gr = r0 + tr4 + i;
            acc[i][0] += b0.x; acc[i][1] += b0.y; acc[i][2] += b0.z; acc[i][3] += b0.w;
            acc[i][4] += b1.x; acc[i][5] += b1.y; acc[i][6] += b1.z; acc[i][7] += b1.w;
            float p = acc[i][0] * aw0.x + acc[i][1] * aw0.y + acc[i][2] * aw0.z + acc[i][3] * aw0.w
                    + acc[i][4] * aw1.x + acc[i][5] * aw1.y + acc[i][6] * aw1.z + acc[i][7] * aw1.w;
            p += __shfl_xor(p, 1);
            p += __shfl_xor(p, 2);
            p += __shfl_xor(p, 4);
            p += __shfl_xor(p, 8);
            if (gr < NSRC) {
                float4* o = reinterpret_cast<float4*>(hs + (size_t)gr * DIM + c0);
                o[0] = make_float4(acc[i][0], acc[i][1], acc[i][2], acc[i][3]);
                o[1] = make_float4(acc[i][4], acc[i][5], acc[i][6], acc[i][7]);
                if (tc == 0) s_score[gr] = p;
            }
        }
    } else if (bid < HS_BLOCKS + DS_BLOCKS) {
        // ---- role 1: d_score = B . wd_vec + scal[0] ----
        int row = (bid - HS_BLOCKS) * 32 + (t >> 3);
        int c0 = (t & 7) * 16;
        if (row >= NDST) return;
        const float4* x = reinterpret_cast<const float4*>(B + (size_t)row * DIM + c0);
        const float4* w = reinterpret_cast<const float4*>(wd_vec + c0);
        float p = 0.f;
        #pragma unroll
        for (int i = 0; i < 4; ++i) {
            float4 a = x[i], b = w[i];
            p += a.x * b.x + a.y * b.y + a.z * b.z + a.w * b.w;
        }
        p += __shfl_xor(p, 1);
        p += __shfl_xor(p, 2);
        p += __shfl_xor(p, 4);
        if ((t & 7) == 0) d_score[row] = p + scal[0];
    } else {
        // ---- role 2: ee[e] = ef[e].we_vec + scal[1] (coalesced) + deg histogram ----
        float wv[EDIM];
        #pragma unroll
        for (int k = 0; k < EDIM; ++k) wv[k] = we_vec[k];
        float s1 = scal[1];
        int ebase = (bid - HS_BLOCKS - DS_BLOCKS) * 1024 + t;
        #pragma unroll
        for (int i = 0; i < 4; ++i) {
            int e = ebase + i * 256;
            if (e < NEDGE) {
                const float* er = ef + (size_t)e * EDIM;
                float a = s1;
                #pragma unroll
                for (int k = 0; k < EDIM; ++k) a += er[k] * wv[k];
                ee[e] = a;
                atomicAdd(&deg[dst_idx[e]], 1);
            }
        }
    }
}

// ---- parallel exclusive scan: A (per-chunk scan), B (scan block totals), C (add base)
__global__ __launch_bounds__(256) void k_scanA(const int* __restrict__ deg,
                                               int* __restrict__ off,
                                               int* __restrict__ partials) {
    __shared__ int tmp[256];
    int t = threadIdx.x;
    int i = blockIdx.x * 256 + t;
    int v = (i < NDST) ? deg[i] : 0;
    tmp[t] = v;
    __syncthreads();
    #pragma unroll
    for (int d = 1; d < 256; d <<= 1) {
        int u = (t >= d) ? tmp[t - d] : 0;
        __syncthreads();
        tmp[t] += u;
        __syncthreads();
    }
    if (i < NDST) off[i] = tmp[t] - v;          // local exclusive prefix
    if (t == 255) partials[blockIdx.x] = tmp[255];
}

__global__ __launch_bounds__(256) void k_scanB(int* __restrict__ partials) {
    __shared__ int tmp[256];
    int t = threadIdx.x;
    int v = (t < SCAN_NBLK) ? partials[t] : 0;
    tmp[t] = v;
    __syncthreads();
    #pragma unroll
    for (int d = 1; d < 256; d <<= 1) {
        int u = (t >= d) ? tmp[t - d] : 0;
        __syncthreads();
        tmp[t] += u;
        __syncthreads();
    }
    if (t < SCAN_NBLK) partials[t] = tmp[t] - v;  // exclusive base per block
}

__global__ __launch_bounds__(256) void k_scanC(int* __restrict__ off,
                                               int* __restrict__ cursor,
                                               const int* __restrict__ partials) {
    int t = threadIdx.x;
    int i = blockIdx.x * 256 + t;
    if (i < NDST) {
        int f = off[i] + partials[blockIdx.x];
        off[i] = f;
        cursor[i] = f;
    }
    if (i == 0) off[NDST] = NEDGE;
}

// scatter pass: w = exp(ee + s_score + d_score); single 8B packed store per edge.
__global__ __launch_bounds__(256) void k_scat(const int* __restrict__ src_idx,
                                              const int* __restrict__ dst_idx,
                                              const float* __restrict__ ee,
                                              const float* __restrict__ s_score,
                                              const float* __restrict__ d_score,
                                              int* __restrict__ cursor,
                                              int2* __restrict__ pairs) {
    int base = blockIdx.x * 1024 + threadIdx.x;
    #pragma unroll
    for (int i = 0; i < 4; ++i) {
        int e = base + i * 256;
        if (e < NEDGE) {
            int s = src_idx[e], d = dst_idx[e];
            // 0.05-scaled weights => |logit| = O(3); exp without max-subtraction
            // is exact softmax algebraically and overflow-free here.
            float w = expf(ee[e] + s_score[s] + d_score[d]);
            int pos = atomicAdd(&cursor[d], 1);
            pairs[pos] = make_int2(s, __float_as_int(w));
        }
    }
}

// one wave per dst row. Batch edge pairs into registers (one coalesced 8B load
// per 64 edges), broadcast via shfl -> all hs gathers issue independently.
__global__ __launch_bounds__(256) void k_gather(const float* __restrict__ hs,
                                                const int* __restrict__ off,
                                                const int2* __restrict__ pairs,
                                                float* __restrict__ h_new) {
    int wid = (blockIdx.x * blockDim.x + threadIdx.x) >> 6;
    int lane = threadIdx.x & 63;
    if (wid >= NDST) return;
    int b = off[wid], e2 = off[wid + 1];
    int deg = e2 - b;
    float ax = 0.f, ay = 0.f, wsum = 0.f;

    for (int base = 0; base < deg; base += 64) {
        int cnt = min(deg - base, 64);
        int myS = 0;
        float myW = 0.f;
        if (lane < cnt) {
            int2 p = pairs[b + base + lane];
            myS = p.x;
            myW = __int_as_float(p.y);
        }
        wsum += myW;

        int j = 0;
        for (; j + 4 <= cnt; j += 4) {
            int s0 = __shfl(myS, j + 0), s1 = __shfl(myS, j + 1);
            int s2 = __shfl(myS, j + 2), s3 = __shfl(myS, j + 3);
            float w0 = __shfl(myW, j + 0), w1 = __shfl(myW, j + 1);
            float w2 = __shfl(myW, j + 2), w3 = __shfl(myW, j + 3);
            float2 v0 = reinterpret_cast<const float2*>(hs + (size_t)s0 * DIM)[lane];
            float2 v1 = reinterpret_cast<const float2*>(hs + (size_t)s1 * DIM)[lane];
            float2 v2 = reinterpret_cast<const float2*>(hs + (size_t)s2 * DIM)[lane];
            float2 v3 = reinterpret_cast<const float2*>(hs + (size_t)s3 * DIM)[lane];
            ax += w0 * v0.x + w1 * v1.x + w2 * v2.x + w3 * v3.x;
            ay += w0 * v0.y + w1 * v1.y + w2 * v2.y + w3 * v3.y;
        }
        for (; j < cnt; ++j) {
            int s0 = __shfl(myS, j);
            float w0 = __shfl(myW, j);
            float2 v0 = reinterpret_cast<const float2*>(hs + (size_t)s0 * DIM)[lane];
            ax += w0 * v0.x;
            ay += w0 * v0.y;
        }
    }

    #pragma unroll
    for (int m = 1; m < 64; m <<= 1) wsum += __shfl_xor(wsum, m);

    float inv = (deg > 0) ? 1.f / wsum : 0.f;  // zero-degree dst -> 0 row (matches ref)
    reinterpret_cast<float2*>(h_new + (size_t)wid * DIM)[lane] = make_float2(ax * inv, ay * inv);
}

// per-column sum / sumsq over h_new
__global__ __launch_bounds__(256) void k_bnstats(const float* __restrict__ h,
                                                 float* __restrict__ colsum,
                                                 float* __restrict__ colsq) {
    int col = threadIdx.x & 127;
    int rp = threadIdx.x >> 7;
    float s = 0.f, q = 0.f;
    for (int r = blockIdx.x * 2 + rp; r < NDST; r += gridDim.x * 2) {
        float x = h[(size_t)r * DIM + col];
        s += x;
        q += x * x;
    }
    __shared__ float ls[2][128], lq[2][128];
    ls[rp][col] = s;
    lq[rp][col] = q;
    __syncthreads();
    if (rp == 0) {
        atomicAdd(&colsum[col], ls[0][col] + ls[1][col]);
        atomicAdd(&colsq[col], lq[0][col] + lq[1][col]);
    }
}

// BN scale/shift computed per-thread in registers (col block fixed under grid-stride)
__global__ __launch_bounds__(256) void k_bnfinal(float* __restrict__ h,
                                                 const float* __restrict__ colsum,
                                                 const float* __restrict__ colsq,
                                                 const float* __restrict__ gamma,
                                                 const float* __restrict__ beta,
                                                 const float* __restrict__ alpha_p) {
    const size_t total4 = (size_t)NDST * DIM / 4;
    const float alpha = alpha_p[0];
    const float invN = 1.f / (float)NDST;
    const int c0 = (threadIdx.x & 31) * 4;
    float sc[4], sh[4];
    #pragma unroll
    for (int k = 0; k < 4; ++k) {
        float mean = colsum[c0 + k] * invN;
        float var = colsq[c0 + k] * invN - mean * mean;
        float s = gamma[c0 + k] * rsqrtf(var + BN_EPS);
        sc[k] = s;
        sh[k] = beta[c0 + k] - mean * s;
    }
    size_t stride = (size_t)gridDim.x * blockDim.x;
    for (size_t i = blockIdx.x * blockDim.x + threadIdx.x; i < total4; i += stride) {
        float4 x = reinterpret_cast<float4*>(h)[i];
        float y0 = x.x * sc[0] + sh[0];
        float y1 = x.y * sc[1] + sh[1];
        float y2 = x.z * sc[2] + sh[2];
        float y3 = x.w * sc[3] + sh[3];
        float4 o;
        o.x = y0 >= 0.f ? y0 : alpha * y0;
        o.y = y1 >= 0.f ? y1 : alpha * y1;
        o.z = y2 >= 0.f ? y2 : alpha * y2;
        o.w = y3 >= 0.f ? y3 : alpha * y3;
        reinterpret_cast<float4*>(h)[i] = o;
    }
}

extern "C" void kernel_launch(void* const* d_in, const int* in_sizes, int n_in,
                              void* d_out, int out_size, void* d_ws, size_t ws_size,
                              hipStream_t stream) {
    const float* src_feat   = (const float*)d_in[0];
    const float* dst_feat   = (const float*)d_in[1];
    const float* edge_feats = (const float*)d_in[2];
    const int*   src_idx    = (const int*)d_in[3];
    const int*   dst_idx    = (const int*)d_in[4];
    const float* W_src      = (const float*)d_in[5];
    const float* b_src      = (const float*)d_in[6];
    const float* W_dst      = (const float*)d_in[7];
    const float* b_dst      = (const float*)d_in[8];
    const float* W_edge     = (const float*)d_in[9];
    const float* b_edge     = (const float*)d_in[10];
    const float* attn_w     = (const float*)d_in[11];
    const float* attn_b     = (const float*)d_in[12];
    const float* gamma      = (const float*)d_in[13];
    const float* beta       = (const float*)d_in[14];
    const float* alpha      = (const float*)d_in[15];

    float* ws      = (float*)d_ws;
    float* hs      = ws + OFF_HS;
    float* s_score = ws + OFF_SSCORE;
    float* d_score = ws + OFF_DSCORE;
    float* ee      = ws + OFF_EE;
    int*   deg     = (int*)(ws + OFF_DEG);
    float* colsum  = ws + OFF_COLSUM;
    float* colsq   = ws + OFF_COLSQ;
    int*   off     = (int*)(ws + OFF_OFFS);
    int*   cursor  = (int*)(ws + OFF_CURSOR);
    int2*  pairs   = (int2*)(ws + OFF_PAIRS);
    float* wd_vec  = ws + OFF_WDVEC;
    float* we_vec  = ws + OFF_WEVEC;
    float* scal    = ws + OFF_SCAL;
    int*   part    = (int*)(ws + OFF_PART);

    float* h_new = (float*)d_out;

    // deg + colsum + colsq are contiguous: one memset
    hipMemsetAsync(deg, 0, (NDST + 256) * sizeof(float), stream);

    k_prep<<<1, 128, 0, stream>>>(W_dst, b_dst, W_edge, b_edge, attn_w, attn_b,
                                  wd_vec, we_vec, scal);
    k_fused<<<HS_BLOCKS + DS_BLOCKS + ED_BLOCKS, 256, 0, stream>>>(
        src_feat, W_src, b_src, attn_w, dst_feat, edge_feats, dst_idx,
        wd_vec, we_vec, scal, hs, s_score, d_score, ee, deg);
    k_scanA<<<SCAN_NBLK, 256, 0, stream>>>(deg, off, part);
    k_scanB<<<1, 256, 0, stream>>>(part);
    k_scanC<<<SCAN_NBLK, 256, 0, stream>>>(off, cursor, part);
    k_scat<<<ED_BLOCKS, 256, 0, stream>>>(src_idx, dst_idx, ee, s_score, d_score,
                                          cursor, pairs);
    k_gather<<<(NDST * 64 + 255) / 256, 256, 0, stream>>>(hs, off, pairs, h_new);
    k_bnstats<<<512, 256, 0, stream>>>(h_new, colsum, colsq);
    k_bnfinal<<<1024, 256, 0, stream>>>(h_new, colsum, colsq, gamma, beta, alpha);
}